// Round 1
// 1728.402 us; speedup vs baseline: 1.0158x; 1.0158x over previous
//
#include <hip/hip_runtime.h>
#include <math.h>
#include <stdint.h>

// ---------------- problem constants ----------------
constexpr int kL = 6;
constexpr int kE = 1024;
constexpr int kH = 16;
constexpr int kF = 4096;
constexpr int kV = 1024;
constexpr int kB = 4;
constexpr int kS = 1024;
constexpr int kRows = kB * kS;   // 4096

typedef __bf16 bf16_t;
typedef __bf16 bf16x8 __attribute__((ext_vector_type(8)));
typedef __bf16 bf16x4 __attribute__((ext_vector_type(4)));
typedef float f32x4 __attribute__((ext_vector_type(4)));
typedef unsigned int u32x2 __attribute__((ext_vector_type(2)));

#define AS1 __attribute__((address_space(1)))
#define AS3 __attribute__((address_space(3)))

__device__ __forceinline__ void gload_lds16(const void* g, void* l) {
  __builtin_amdgcn_global_load_lds((const AS1 unsigned int*)g, (AS3 unsigned int*)l, 16, 0, 0);
}

__device__ __forceinline__ unsigned lds_u32(const void* p) {
  return (unsigned)(uintptr_t)p;
}

__device__ __forceinline__ float gelu_f(float x) {
  return 0.5f * x * (1.0f + erff(x * 0.70710678118654752440f));
}

// ---------------- f32 -> bf16 cast ----------------
__global__ void cast_kernel(const float* __restrict__ in, bf16_t* __restrict__ out, int n4) {
  const int stride = gridDim.x * blockDim.x;
  for (int i = blockIdx.x * blockDim.x + threadIdx.x; i < n4; i += stride) {
    const float4 v = *(const float4*)(in + (size_t)i * 4);
    bf16x4 o;
    o[0] = (bf16_t)v.x; o[1] = (bf16_t)v.y; o[2] = (bf16_t)v.z; o[3] = (bf16_t)v.w;
    *(bf16x4*)(out + (size_t)i * 4) = o;
  }
}

// ---------------- embedding ----------------
__global__ void embed_kernel(const int* __restrict__ seq, const float* __restrict__ emb,
                             const float* __restrict__ pos, float* __restrict__ x32,
                             bf16_t* __restrict__ xb) {
  const int r = blockIdx.x;
  const int s = r & 1023;
  const int tok = seq[r];
  const int c = threadIdx.x << 2;
  const float4 e = *(const float4*)(emb + (size_t)tok * kE + c);
  const float4 pz = *(const float4*)(pos + (size_t)s * kE + c);
  float4 v;
  v.x = e.x * 32.0f + pz.x;
  v.y = e.y * 32.0f + pz.y;
  v.z = e.z * 32.0f + pz.z;
  v.w = e.w * 32.0f + pz.w;
  *(float4*)(x32 + (size_t)r * kE + c) = v;
  bf16x4 o;
  o[0] = (bf16_t)v.x; o[1] = (bf16_t)v.y; o[2] = (bf16_t)v.z; o[3] = (bf16_t)v.w;
  *(bf16x4*)(xb + (size_t)r * kE + c) = o;
}

// ---------------- residual add + LayerNorm ----------------
// MODE 0: x32 = LN(x32 + res_bf16), write bf16 copy.
// MODE 1: bf16 out only, no residual (final LN).
// MODE 2: x32 = LN(x32 + sum of 4 bf16 partials + bias2), write bf16 copy.
template <int MODE>
__global__ void addln_kernel(float* __restrict__ x32, const void* __restrict__ res,
                             const float* __restrict__ gg, const float* __restrict__ bb,
                             bf16_t* __restrict__ xb, const float* __restrict__ bias2) {
  __shared__ float red[8];
  const int r = blockIdx.x;
  const int c = threadIdx.x << 2;
  float4 v = *(const float4*)(x32 + (size_t)r * kE + c);
  if (MODE == 0) {
    const bf16x4 t = *(const bf16x4*)((const bf16_t*)res + (size_t)r * kE + c);
    v.x += (float)t[0]; v.y += (float)t[1]; v.z += (float)t[2]; v.w += (float)t[3];
  }
  if (MODE == 2) {
    const bf16_t* p = (const bf16_t*)res;
#pragma unroll
    for (int part = 0; part < 4; ++part) {
      const bf16x4 t = *(const bf16x4*)(p + (size_t)part * kRows * kE + (size_t)r * kE + c);
      v.x += (float)t[0]; v.y += (float)t[1]; v.z += (float)t[2]; v.w += (float)t[3];
    }
    const float4 b2 = *(const float4*)(bias2 + c);
    v.x += b2.x; v.y += b2.y; v.z += b2.z; v.w += b2.w;
  }
  float s = v.x + v.y + v.z + v.w;
  float q = v.x * v.x + v.y * v.y + v.z * v.z + v.w * v.w;
#pragma unroll
  for (int off = 32; off >= 1; off >>= 1) {
    s += __shfl_xor(s, off, 64);
    q += __shfl_xor(q, off, 64);
  }
  const int w = threadIdx.x >> 6, lane = threadIdx.x & 63;
  if (lane == 0) { red[w] = s; red[4 + w] = q; }
  __syncthreads();
  s = red[0] + red[1] + red[2] + red[3];
  q = red[4] + red[5] + red[6] + red[7];
  const float mean = s * (1.0f / 1024.0f);
  const float var = q * (1.0f / 1024.0f) - mean * mean;
  const float rstd = rsqrtf(var + 1e-5f);
  const float4 g4 = *(const float4*)(gg + c);
  const float4 b4 = *(const float4*)(bb + c);
  float4 o;
  o.x = (v.x - mean) * rstd * g4.x + b4.x;
  o.y = (v.y - mean) * rstd * g4.y + b4.y;
  o.z = (v.z - mean) * rstd * g4.z + b4.z;
  o.w = (v.w - mean) * rstd * g4.w + b4.w;
  if (MODE != 1) *(float4*)(x32 + (size_t)r * kE + c) = o;
  bf16x4 ob;
  ob[0] = (bf16_t)o.x; ob[1] = (bf16_t)o.y; ob[2] = (bf16_t)o.z; ob[3] = (bf16_t)o.w;
  *(bf16x4*)(xb + (size_t)r * kE + c) = ob;
}

// ---------------- GEMM 128x128 (m97-style) — logits only ----------------
template <int EPI>
__launch_bounds__(256, 3)
__global__ void gemm_bt_kernel(const bf16_t* __restrict__ A, const bf16_t* __restrict__ Bt,
                               const float* __restrict__ bias, void* __restrict__ Cv,
                               int M, int N, int K) {
  __shared__ bf16_t lA[128 * 32];
  __shared__ bf16_t lB[128 * 32];
  const int tid = threadIdx.x;
  const int w = tid >> 6;
  const int lane = tid & 63;
  const int g = lane >> 4;
  const int lr = lane & 15;
  const int bm0 = blockIdx.y << 7;
  const int bn0 = blockIdx.x << 7;
  const int wm = (w >> 1) << 6;
  const int wn = (w & 1) << 6;

  const int sr = lane >> 2;
  const int sc = (lane & 3) << 4;

  const char* srcA0 = (const char*)(A + (size_t)(bm0 + (w << 5) + sr) * K) + sc;
  const char* srcA1 = (const char*)(A + (size_t)(bm0 + (w << 5) + 16 + sr) * K) + sc;
  const char* srcB0 = (const char*)(Bt + (size_t)(bn0 + (w << 5) + sr) * K) + sc;
  const char* srcB1 = (const char*)(Bt + (size_t)(bn0 + (w << 5) + 16 + sr) * K) + sc;
  bf16_t* dA0 = lA + (size_t)(w << 5) * 32;
  bf16_t* dA1 = lA + (size_t)((w << 5) + 16) * 32;
  bf16_t* dB0 = lB + (size_t)(w << 5) * 32;
  bf16_t* dB1 = lB + (size_t)((w << 5) + 16) * 32;

  f32x4 zz = {0.f, 0.f, 0.f, 0.f};
  f32x4 acc[4][4];
#pragma unroll
  for (int i = 0; i < 4; ++i)
#pragma unroll
    for (int j = 0; j < 4; ++j) acc[i][j] = zz;

  const bf16_t* pa[4];
  const bf16_t* pb[4];
#pragma unroll
  for (int i = 0; i < 4; ++i) {
    pa[i] = lA + (size_t)(wm + i * 16 + lr) * 32 + g * 8;
    pb[i] = lB + (size_t)(wn + i * 16 + lr) * 32 + g * 8;
  }

  const int NT = K >> 5;
  for (int t = 0; t < NT; ++t) {
    gload_lds16(srcA0, dA0);
    gload_lds16(srcA1, dA1);
    gload_lds16(srcB0, dB0);
    gload_lds16(srcB1, dB1);
    srcA0 += 64; srcA1 += 64; srcB0 += 64; srcB1 += 64;
    __syncthreads();
    bf16x8 a[4], b[4];
#pragma unroll
    for (int i = 0; i < 4; ++i) a[i] = *(const bf16x8*)pa[i];
#pragma unroll
    for (int i = 0; i < 4; ++i) b[i] = *(const bf16x8*)pb[i];
#pragma unroll
    for (int i = 0; i < 4; ++i)
#pragma unroll
      for (int j = 0; j < 4; ++j)
        acc[i][j] = __builtin_amdgcn_mfma_f32_16x16x32_bf16(a[i], b[j], acc[i][j], 0, 0, 0);
    __syncthreads();
  }

#pragma unroll
  for (int i = 0; i < 4; ++i) {
#pragma unroll
    for (int j = 0; j < 4; ++j) {
      const int col = bn0 + wn + j * 16 + lr;
      const float bv = bias[col];
#pragma unroll
      for (int rg = 0; rg < 4; ++rg) {
        const int row = bm0 + wm + i * 16 + g * 4 + rg;
        float v = acc[i][j][rg] + bv;
        if (EPI == 1) {
          ((float*)Cv)[(size_t)row * N + col] = v;
        } else {
          ((bf16_t*)Cv)[(size_t)row * N + col] = (bf16_t)v;
        }
      }
    }
  }
}

// ---------------- GEMM 256x256, BK=64, 8 waves, 8-phase counted-vmcnt ----------------
// T2 swizzle (XOR (row&7)<<4 on byte col, pre-applied to global source) +
// T3/T4 (4 phases/K-tile, 1 stage-region/phase, vmcnt(6) once per K-tile) + T5 setprio.
// Region plan (per K-tile, quadrants (ih,jh)):
//   P1: reads a[0-3][kk0,kk1] + b[0-1][*] (12 ds_read); MFMA i0-3,j0-1; stage A-ih1(t+1)->buf^1
//   P2: reads b[2-3][*] (4);              MFMA i0-3,j2-3; stage A-ih0(t+2)->buf
//   P3: reads a[4-7][*] (8);              MFMA i4-7,j0-1; stage B-jh0(t+2)->buf
//   P4: no reads;                         MFMA i4-7,j2-3; stage B-jh1(t+2)->buf; vmcnt(6)
// Each region's LDS rows were last ds_read >=1 barrier before its re-stage (race-free).
// EPI: 0 = bias->bf16, 2 = bias+GELU->bf16, 3 = nobias->bf16 partial (out += z*zstride)
template <int EPI>
__launch_bounds__(512, 2)
__global__ void gemm256_kernel(const bf16_t* __restrict__ A, const bf16_t* __restrict__ Bt,
                               const float* __restrict__ bias, void* __restrict__ Cv,
                               int ldA, int ldB, int ldC, int kc, size_t zstride) {
  __shared__ bf16_t lA[2][256 * 64];
  __shared__ bf16_t lB[2][256 * 64];
  const int tid = threadIdx.x;
  const int w = tid >> 6, lane = tid & 63, g = lane >> 4, lr = lane & 15;

  // T1: XCD-aware bijective swizzle (all grids have nwg % 8 == 0)
  const int nwg = gridDim.x * gridDim.y;
  const int lin = blockIdx.y * gridDim.x + blockIdx.x;
  const int cpx = nwg >> 3;
  const int swz = (lin & 7) * cpx + (lin >> 3);
  const int bx = swz % gridDim.x, by = swz / gridDim.x;
  const int bm0 = by << 8, bn0 = bx << 8;
  const int wr = w >> 2, wc = w & 3;
  const int wm = wr << 7, wn = wc << 6;
  const int k0 = blockIdx.z * kc;

  // per-lane staging source (swizzle pre-applied: col granule ^ row-within-8)
  const int lrow = lane >> 3, lcol8 = lane & 7;
  const int scol = ((lcol8 ^ lrow) << 3);
  const bf16_t* pA = A + (size_t)(bm0 + lrow) * ldA + k0 + scol;
  const bf16_t* pB = Bt + (size_t)(bn0 + lrow) * ldB + k0 + scol;

  // per-wave stage region row-bases (all multiples of 8)
  const int ra1_0 = w * 8,                        ra1_1 = 128 + w * 8;  // A ih0
  const int ra4_0 = 64 + w * 8,                   ra4_1 = 192 + w * 8;  // A ih1
  const int rb2_0 = (w >> 2) * 64 + (w & 3) * 8,  rb2_1 = rb2_0 + 128;  // B jh0
  const int rb3_0 = rb2_0 + 32,                   rb3_1 = rb2_1 + 32;   // B jh1

#define STG_A(bufi, t, rb) gload_lds16(pA + (size_t)(rb) * ldA + (t) * 64, &lA[bufi][(rb) * 64])
#define STG_B(bufi, t, rb) gload_lds16(pB + (size_t)(rb) * ldB + (t) * 64, &lB[bufi][(rb) * 64])
#define STAGE_R1(bufi, t) { STG_A(bufi, t, ra1_0); STG_A(bufi, t, ra1_1); }
#define STAGE_R2(bufi, t) { STG_B(bufi, t, rb2_0); STG_B(bufi, t, rb2_1); }
#define STAGE_R3(bufi, t) { STG_B(bufi, t, rb3_0); STG_B(bufi, t, rb3_1); }
#define STAGE_R4(bufi, t) { STG_A(bufi, t, ra4_0); STG_A(bufi, t, ra4_1); }

  // swizzled ds_read column offsets (elements)
  const int cs0 = (g * 8) ^ ((lr & 7) << 3);
  const int cs1 = (32 + g * 8) ^ ((lr & 7) << 3);
#define LDA8(bufi, row, cs) (*(const bf16x8*)&lA[bufi][(row) * 64 + (cs)])
#define LDB8(bufi, row, cs) (*(const bf16x8*)&lB[bufi][(row) * 64 + (cs)])

#define PH_MID()                                          \
  __builtin_amdgcn_sched_barrier(0);                      \
  __builtin_amdgcn_s_barrier();                           \
  asm volatile("s_waitcnt lgkmcnt(0)" ::: "memory");      \
  __builtin_amdgcn_sched_barrier(0);                      \
  __builtin_amdgcn_s_setprio(1)

#define PH_END()                                          \
  __builtin_amdgcn_s_setprio(0);                          \
  __builtin_amdgcn_sched_barrier(0);                      \
  __builtin_amdgcn_s_barrier();                           \
  __builtin_amdgcn_sched_barrier(0)

#define PH_END_VM()                                       \
  __builtin_amdgcn_s_setprio(0);                          \
  __builtin_amdgcn_sched_barrier(0);                      \
  asm volatile("s_waitcnt vmcnt(6)" ::: "memory");        \
  __builtin_amdgcn_s_barrier();                           \
  __builtin_amdgcn_sched_barrier(0)

  f32x4 zz = {0.f, 0.f, 0.f, 0.f};
  f32x4 acc[8][4];
#pragma unroll
  for (int i = 0; i < 8; ++i)
#pragma unroll
    for (int j = 0; j < 4; ++j) acc[i][j] = zz;

  const int NT = kc >> 6;  // >= 2 required (here 4 or 16)

  // prologue: R1..R4 of tile0, R1..R3 of tile1; then tile0 fully landed.
  STAGE_R1(0, 0); STAGE_R2(0, 0); STAGE_R3(0, 0); STAGE_R4(0, 0);
  STAGE_R1(1, 1); STAGE_R2(1, 1); STAGE_R3(1, 1);
  asm volatile("s_waitcnt vmcnt(6)" ::: "memory");
  __builtin_amdgcn_s_barrier();
  __builtin_amdgcn_sched_barrier(0);

  bf16x8 a0[4][2], a1[4][2], b[4][2];

  for (int t = 0; t < NT; ++t) {
    const int bz = t & 1;
    // ---------------- P1 ----------------
#pragma unroll
    for (int i = 0; i < 4; ++i) {
      a0[i][0] = LDA8(bz, wm + i * 16 + lr, cs0);
      a0[i][1] = LDA8(bz, wm + i * 16 + lr, cs1);
    }
#pragma unroll
    for (int j = 0; j < 2; ++j) {
      b[j][0] = LDB8(bz, wn + j * 16 + lr, cs0);
      b[j][1] = LDB8(bz, wn + j * 16 + lr, cs1);
    }
    if (t + 1 < NT) STAGE_R4(bz ^ 1, t + 1);
    PH_MID();
#pragma unroll
    for (int i = 0; i < 4; ++i)
#pragma unroll
      for (int j = 0; j < 2; ++j) {
        acc[i][j] = __builtin_amdgcn_mfma_f32_16x16x32_bf16(a0[i][0], b[j][0], acc[i][j], 0, 0, 0);
        acc[i][j] = __builtin_amdgcn_mfma_f32_16x16x32_bf16(a0[i][1], b[j][1], acc[i][j], 0, 0, 0);
      }
    PH_END();
    // ---------------- P2 ----------------
#pragma unroll
    for (int j = 2; j < 4; ++j) {
      b[j][0] = LDB8(bz, wn + j * 16 + lr, cs0);
      b[j][1] = LDB8(bz, wn + j * 16 + lr, cs1);
    }
    if (t + 2 < NT) STAGE_R1(bz, t + 2);
    PH_MID();
#pragma unroll
    for (int i = 0; i < 4; ++i)
#pragma unroll
      for (int j = 2; j < 4; ++j) {
        acc[i][j] = __builtin_amdgcn_mfma_f32_16x16x32_bf16(a0[i][0], b[j][0], acc[i][j], 0, 0, 0);
        acc[i][j] = __builtin_amdgcn_mfma_f32_16x16x32_bf16(a0[i][1], b[j][1], acc[i][j], 0, 0, 0);
      }
    PH_END();
    // ---------------- P3 ----------------
#pragma unroll
    for (int i = 0; i < 4; ++i) {
      a1[i][0] = LDA8(bz, wm + 64 + i * 16 + lr, cs0);
      a1[i][1] = LDA8(bz, wm + 64 + i * 16 + lr, cs1);
    }
    if (t + 2 < NT) STAGE_R2(bz, t + 2);
    PH_MID();
#pragma unroll
    for (int i = 0; i < 4; ++i)
#pragma unroll
      for (int j = 0; j < 2; ++j) {
        acc[4 + i][j] = __builtin_amdgcn_mfma_f32_16x16x32_bf16(a1[i][0], b[j][0], acc[4 + i][j], 0, 0, 0);
        acc[4 + i][j] = __builtin_amdgcn_mfma_f32_16x16x32_bf16(a1[i][1], b[j][1], acc[4 + i][j], 0, 0, 0);
      }
    PH_END();
    // ---------------- P4 ----------------
    if (t + 2 < NT) STAGE_R3(bz, t + 2);
    PH_MID();
#pragma unroll
    for (int i = 0; i < 4; ++i)
#pragma unroll
      for (int j = 2; j < 4; ++j) {
        acc[4 + i][j] = __builtin_amdgcn_mfma_f32_16x16x32_bf16(a1[i][0], b[j][0], acc[4 + i][j], 0, 0, 0);
        acc[4 + i][j] = __builtin_amdgcn_mfma_f32_16x16x32_bf16(a1[i][1], b[j][1], acc[4 + i][j], 0, 0, 0);
      }
    PH_END_VM();
  }

  // epilogue: C/D layout col = lane&15, row = (lane>>4)*4 + reg
  bf16_t* outb = (bf16_t*)Cv;
  if (EPI == 3) outb += (size_t)blockIdx.z * zstride;
#pragma unroll
  for (int i = 0; i < 8; ++i) {
#pragma unroll
    for (int j = 0; j < 4; ++j) {
      const int col = bn0 + wn + j * 16 + lr;
      float bv = 0.0f;
      if (EPI != 3) bv = bias[col];
#pragma unroll
      for (int rg = 0; rg < 4; ++rg) {
        const int row = bm0 + wm + i * 16 + g * 4 + rg;
        float v = acc[i][j][rg] + bv;
        if (EPI == 2) v = gelu_f(v);
        outb[(size_t)row * ldC + col] = (bf16_t)v;
      }
    }
  }
#undef STG_A
#undef STG_B
#undef STAGE_R1
#undef STAGE_R2
#undef STAGE_R3
#undef STAGE_R4
#undef LDA8
#undef LDB8
#undef PH_MID
#undef PH_END
#undef PH_END_VM
}

// ---------------- fused causal attention with relative-distance bias ----------------
// v2: latency-pipelined. Double-buffered V tile (vbuf[2]) + next-tile K fragments
// prefetched into a second register set, issued BEFORE the current tile's compute, so
// the single per-iteration __syncthreads (vmcnt(0) drain) overlaps compute instead of
// serializing ~500-900 cy of HBM/L2 latency per KV tile. nt = 2*qt+2 is always even ->
// unroll-by-2 ping-pong with static register indexing. Pad flags precomputed in LDS.
// Heavy q-tiles dispatched first (qt = 15 - (bid&15)). launch_bounds(256,4) keeps
// VGPR <= 128 so all 1024 blocks stay co-resident (4 blocks/CU).
__launch_bounds__(256, 4)
__global__ void attn_kernel(const bf16_t* __restrict__ qkv, const int* __restrict__ seq,
                            const float* __restrict__ dist_emb, bf16_t* __restrict__ ctx) {
  __shared__ float sbias[1024];
  __shared__ unsigned char spad[1024];
  __shared__ bf16_t vbuf[2][2048];
  __shared__ bf16_t pbuf[4][16][36];
  const int tid = threadIdx.x;
  const int w = tid >> 6, lane = tid & 63, g = lane >> 4, lr = lane & 15;
  const int bid = blockIdx.x;
  const int qt = 15 - (bid & 15), h = (bid >> 4) & 15, b = bid >> 8;

  const int q0 = qt * 64 + w * 16;
  const int qrow = q0 + lr;
  const bf16_t* qp = qkv + ((size_t)(b * kS + qrow)) * 3072 + h * 64;

  // V staging source (tr-read-friendly swizzle, unchanged)
  const int p = (w * 64 + lane) * 16;
  const int s_kv = ((p >> 11) << 4) + ((p >> 5) & 15);
  const int s_dv = (((p >> 9) & 3) << 4) + ((p & 31) >> 1);
  const bf16_t* vsrc0 = qkv + ((size_t)(b * kS + s_kv)) * 3072 + 2048 + h * 64 + s_dv;

  const bf16_t* kbase = qkv + (size_t)b * kS * 3072 + 1024 + h * 64;
  const int* seqb = seq + b * kS;
  const int qmaxw = q0 + 15;
  const int nt = qt * 2 + 2;

#define STAGEV(bufi, kt_) gload_lds16(vsrc0 + (size_t)(kt_) * 32 * 3072, &vbuf[bufi][w << 9])
#define LOADK(d0, d1, d2, d3, kt_) {                                        \
    const bf16_t* kp0 = kbase + (size_t)((kt_) * 32 + lr) * 3072;           \
    const bf16_t* kp1 = kp0 + 16 * 3072;                                    \
    d0 = *(const bf16x8*)(kp0 + g * 8);                                     \
    d1 = *(const bf16x8*)(kp0 + 32 + g * 8);                                \
    d2 = *(const bf16x8*)(kp1 + g * 8);                                     \
    d3 = *(const bf16x8*)(kp1 + 32 + g * 8);                                \
  }

  // prologue: issue tile-0 V stage + K loads first so they hide under the
  // sbias/spad fill and Q loads.
  bf16x8 kA0, kA1, kA2, kA3, kB0, kB1, kB2, kB3;
  STAGEV(0, 0);
  LOADK(kA0, kA1, kA2, kA3, 0);

  const bf16x8 qf0 = *(const bf16x8*)(qp + g * 8);
  const bf16x8 qf1 = *(const bf16x8*)(qp + 32 + g * 8);

  for (int i = tid; i < 1024; i += 256) {
    sbias[i] = dist_emb[i * kH + h];
    spad[i] = (seqb[i] == kV - 1) ? 1 : 0;
  }

  f32x4 zz = {0.f, 0.f, 0.f, 0.f};
  f32x4 oacc[4];
#pragma unroll
  for (int n = 0; n < 4; ++n) oacc[n] = zz;
  float m_[4], l_[4];
#pragma unroll
  for (int j = 0; j < 4; ++j) { m_[j] = -1e30f; l_[j] = 0.f; }

  __syncthreads();  // tile-0 V landed, spad/sbias visible

#define ATT_STEP(kt_, bufi, kf00, kf01, kf10, kf11) do {                      \
    f32x4 s0 = zz, s1 = zz;                                                   \
    s0 = __builtin_amdgcn_mfma_f32_16x16x32_bf16(qf0, (kf00), s0, 0, 0, 0);   \
    s0 = __builtin_amdgcn_mfma_f32_16x16x32_bf16(qf1, (kf01), s0, 0, 0, 0);   \
    s1 = __builtin_amdgcn_mfma_f32_16x16x32_bf16(qf0, (kf10), s1, 0, 0, 0);   \
    s1 = __builtin_amdgcn_mfma_f32_16x16x32_bf16(qf1, (kf11), s1, 0, 0, 0);   \
    const int col0 = (kt_) * 32 + lr;                                         \
    const int col1 = col0 + 16;                                               \
    const bool pad0 = spad[col0] != 0;                                        \
    const bool pad1 = spad[col1] != 0;                                        \
    float sv0[4], sv1[4], mj[4];                                              \
    _Pragma("unroll")                                                         \
    for (int j = 0; j < 4; ++j) {                                             \
      const int r = q0 + g * 4 + j;                                           \
      const float v0 =                                                        \
          (col0 <= r && !pad0) ? s0[j] * 0.125f + sbias[r - col0] : -1e30f;   \
      const float v1 =                                                        \
          (col1 <= r && !pad1) ? s1[j] * 0.125f + sbias[r - col1] : -1e30f;   \
      sv0[j] = v0; sv1[j] = v1;                                               \
      mj[j] = fmaxf(v0, v1);                                                  \
    }                                                                         \
    _Pragma("unroll")                                                         \
    for (int off = 1; off < 16; off <<= 1) {                                  \
      _Pragma("unroll")                                                       \
      for (int j = 0; j < 4; ++j) mj[j] = fmaxf(mj[j], __shfl_xor(mj[j], off, 64)); \
    }                                                                         \
    float corr[4], rs[4], pv0[4], pv1[4];                                     \
    _Pragma("unroll")                                                         \
    for (int j = 0; j < 4; ++j) {                                             \
      const float mn = fmaxf(m_[j], mj[j]);                                   \
      corr[j] = __expf(m_[j] - mn);                                           \
      m_[j] = mn;                                                             \
      pv0[j] = __expf(sv0[j] - mn);                                           \
      pv1[j] = __expf(sv1[j] - mn);                                           \
      rs[j] = pv0[j] + pv1[j];                                                \
    }                                                                         \
    _Pragma("unroll")                                                         \
    for (int off = 1; off < 16; off <<= 1) {                                  \
      _Pragma("unroll")                                                       \
      for (int j = 0; j < 4; ++j) rs[j] += __shfl_xor(rs[j], off, 64);        \
    }                                                                         \
    _Pragma("unroll")                                                         \
    for (int j = 0; j < 4; ++j) l_[j] = l_[j] * corr[j] + rs[j];              \
    _Pragma("unroll")                                                         \
    for (int n = 0; n < 4; ++n) {                                             \
      f32x4 t = oacc[n];                                                      \
      t[0] *= corr[0]; t[1] *= corr[1]; t[2] *= corr[2]; t[3] *= corr[3];     \
      oacc[n] = t;                                                            \
    }                                                                         \
    _Pragma("unroll")                                                         \
    for (int j = 0; j < 4; ++j) {                                             \
      pbuf[w][g * 4 + j][lr] = (bf16_t)pv0[j];                                \
      pbuf[w][g * 4 + j][16 + lr] = (bf16_t)pv1[j];                           \
    }                                                                         \
    asm volatile("s_waitcnt lgkmcnt(0)" ::: "memory");                        \
    const bf16x4 pa0 = *(const bf16x4*)&pbuf[w][lr][g * 4];                   \
    const bf16x4 pa1 = *(const bf16x4*)&pbuf[w][lr][16 + g * 4];              \
    bf16x8 pf;                                                                \
    _Pragma("unroll")                                                         \
    for (int j = 0; j < 4; ++j) { pf[j] = pa0[j]; pf[4 + j] = pa1[j]; }       \
    const unsigned vb0 = lds_u32(&vbuf[bufi][0]) + g * 128 + lr * 8;          \
    u32x2 vt[8];                                                              \
    _Pragma("unroll")                                                         \
    for (int n = 0; n < 4; ++n) {                                             \
      asm volatile("ds_read_b64_tr_b16 %0, %2\n\t"                            \
                   "ds_read_b64_tr_b16 %1, %2 offset:2048"                    \
                   : "=&v"(vt[n * 2]), "=&v"(vt[n * 2 + 1])                   \
                   : "v"(vb0 + n * 512)                                       \
                   : "memory");                                               \
    }                                                                         \
    asm volatile("s_waitcnt lgkmcnt(0)" ::: "memory");                        \
    __builtin_amdgcn_sched_barrier(0);                                        \
    _Pragma("unroll")                                                         \
    for (int n = 0; n < 4; ++n) {                                             \
      const bf16x4 v0 = __builtin_bit_cast(bf16x4, vt[n * 2]);                \
      const bf16x4 v1 = __builtin_bit_cast(bf16x4, vt[n * 2 + 1]);            \
      bf16x8 vf;                                                              \
      _Pragma("unroll")                                                       \
      for (int j = 0; j < 4; ++j) { vf[j] = v0[j]; vf[4 + j] = v1[j]; }       \
      oacc[n] = __builtin_amdgcn_mfma_f32_16x16x32_bf16(pf, vf, oacc[n], 0, 0, 0); \
    }                                                                         \
  } while (0)

  // nt is always even -> unroll-by-2 ping-pong, no tail.
  for (int kt = 0; kt < nt; kt += 2) {
    // even step: compute(buf0, kA); prefetch kt+1 -> buf1/kB
    STAGEV(1, kt + 1);
    LOADK(kB0, kB1, kB2, kB3, kt + 1);
    if (kt * 32 <= qmaxw) ATT_STEP(kt, 0, kA0, kA1, kA2, kA3);
    __syncthreads();
    // odd step: compute(buf1, kB); prefetch kt+2 -> buf0/kA
    if (kt + 2 < nt) {
      STAGEV(0, kt + 2);
      LOADK(kA0, kA1, kA2, kA3, kt + 2);
    }
    if ((kt + 1) * 32 <= qmaxw) ATT_STEP(kt + 1, 1, kB0, kB1, kB2, kB3);
    __syncthreads();
  }
#undef ATT_STEP
#undef STAGEV
#undef LOADK

#pragma unroll
  for (int j = 0; j < 4; ++j) {
    const float inv = 1.0f / l_[j];
    const int r = q0 + g * 4 + j;
    bf16_t* dst = ctx + ((size_t)(b * kS + r)) * kE + h * 64;
#pragma unroll
    for (int n = 0; n < 4; ++n) dst[n * 16 + lr] = (bf16_t)(oacc[n][j] * inv);
  }
}

// ---------------- host ----------------
extern "C" void kernel_launch(void* const* d_in, const int* in_sizes, int n_in,
                              void* d_out, int out_size, void* d_ws, size_t ws_size,
                              hipStream_t stream) {
  (void)in_sizes; (void)n_in; (void)out_size;
  const int* seq = (const int*)d_in[0];
  const float* emb = (const float*)d_in[1];
  const float* pos = (const float*)d_in[2];
  const float* dist = (const float*)d_in[3];
  const float* in_w = (const float*)d_in[4];
  const float* in_b = (const float*)d_in[5];
  const float* out_w = (const float*)d_in[6];
  const float* out_b = (const float*)d_in[7];
  const float* ln1g = (const float*)d_in[8];
  const float* ln1b = (const float*)d_in[9];
  const float* ff1w = (const float*)d_in[10];
  const float* ff1b = (const float*)d_in[11];
  const float* ff2w = (const float*)d_in[12];
  const float* ff2b = (const float*)d_in[13];
  const float* ln2g = (const float*)d_in[14];
  const float* ln2b = (const float*)d_in[15];
  const float* lnfg = (const float*)d_in[16];
  const float* lnfb = (const float*)d_in[17];
  const float* genw = (const float*)d_in[18];
  const float* genb = (const float*)d_in[19];

  char* ws = (char*)d_ws;
  size_t off = 0;
  auto alloc = [&](size_t elems, size_t esz) -> void* {
    void* pp = ws + off;
    off += (elems * esz + 255) & ~(size_t)255;
    return pp;
  };
  bf16_t* w_in = (bf16_t*)alloc((size_t)kL * 3 * kE * kE, 2);
  bf16_t* w_out = (bf16_t*)alloc((size_t)kL * kE * kE, 2);
  bf16_t* w_f1 = (bf16_t*)alloc((size_t)kL * kF * kE, 2);
  bf16_t* w_f2 = (bf16_t*)alloc((size_t)kL * kE * kF, 2);
  bf16_t* w_g = (bf16_t*)alloc((size_t)kV * kE, 2);
  float* x32 = (float*)alloc((size_t)kRows * kE, 4);
  bf16_t* xb = (bf16_t*)alloc((size_t)kRows * kE, 2);
  bf16_t* qkvb = (bf16_t*)alloc((size_t)kRows * 3 * kE, 2);
  bf16_t* ctxb = (bf16_t*)alloc((size_t)kRows * kE, 2);
  bf16_t* tmp4 = (bf16_t*)alloc((size_t)4 * kRows * kE, 2);  // split-K partials
  bf16_t* hb = (bf16_t*)alloc((size_t)kRows * kF, 2);
  if (off > ws_size) return;

  cast_kernel<<<2048, 256, 0, stream>>>(in_w, w_in, kL * 3 * kE * kE / 4);
  cast_kernel<<<2048, 256, 0, stream>>>(out_w, w_out, kL * kE * kE / 4);
  cast_kernel<<<2048, 256, 0, stream>>>(ff1w, w_f1, kL * kF * kE / 4);
  cast_kernel<<<2048, 256, 0, stream>>>(ff2w, w_f2, kL * kE * kF / 4);
  cast_kernel<<<1024, 256, 0, stream>>>(genw, w_g, kV * kE / 4);
  embed_kernel<<<kRows, 256, 0, stream>>>(seq, emb, pos, x32, xb);

  for (int l = 0; l < kL; ++l) {
    // QKV: [4096,1024] x [3072,1024]^T -> bf16 [4096,3072]
    gemm256_kernel<0><<<dim3(3 * kE / 256, kRows / 256), 512, 0, stream>>>(
        xb, w_in + (size_t)l * 3 * kE * kE, in_b + (size_t)l * 3 * kE, qkvb,
        kE, kE, 3 * kE, kE, 0);
    attn_kernel<<<kB * kH * 16, 256, 0, stream>>>(qkvb, seq, dist, ctxb);
    // proj: split-K x4 (kc=256) -> 4 bf16 partials; bias folded into addln
    gemm256_kernel<3><<<dim3(kE / 256, kRows / 256, 4), 512, 0, stream>>>(
        ctxb, w_out + (size_t)l * kE * kE, nullptr, tmp4,
        kE, kE, kE, 256, (size_t)kRows * kE);
    addln_kernel<2><<<kRows, 256, 0, stream>>>(x32, tmp4, ln1g + (size_t)l * kE,
                                               ln1b + (size_t)l * kE, xb, out_b + (size_t)l * kE);
    // FF1: [4096,1024] x [4096,1024]^T + bias + GELU -> bf16 [4096,4096]
    gemm256_kernel<2><<<dim3(kF / 256, kRows / 256), 512, 0, stream>>>(
        xb, w_f1 + (size_t)l * kF * kE, ff1b + (size_t)l * kF, hb,
        kE, kE, kF, kE, 0);
    // FF2: split-K x4 (kc=1024): [4096,4096] x [1024,4096]^T -> 4 bf16 partials
    gemm256_kernel<3><<<dim3(kE / 256, kRows / 256, 4), 512, 0, stream>>>(
        hb, w_f2 + (size_t)l * kE * kF, nullptr, tmp4,
        kF, kF, kE, kE, (size_t)kRows * kE);
    addln_kernel<2><<<kRows, 256, 0, stream>>>(x32, tmp4, ln2g + (size_t)l * kE,
                                               ln2b + (size_t)l * kE, xb, ff2b + (size_t)l * kE);
  }
  addln_kernel<1><<<kRows, 256, 0, stream>>>(x32, nullptr, lnfg, lnfb, xb, nullptr);
  gemm_bt_kernel<1><<<dim3(kV / 128, kRows / 128), 256, 0, stream>>>(
      xb, w_g, genb, (float*)d_out, kRows, kV, kE);
}

// Round 2
// 1417.110 us; speedup vs baseline: 1.2389x; 1.2197x over previous
//
#include <hip/hip_runtime.h>
#include <math.h>
#include <stdint.h>

// ---------------- problem constants ----------------
constexpr int kL = 6;
constexpr int kE = 1024;
constexpr int kH = 16;
constexpr int kF = 4096;
constexpr int kV = 1024;
constexpr int kB = 4;
constexpr int kS = 1024;
constexpr int kRows = kB * kS;   // 4096

typedef __bf16 bf16_t;
typedef __bf16 bf16x8 __attribute__((ext_vector_type(8)));
typedef __bf16 bf16x4 __attribute__((ext_vector_type(4)));
typedef float f32x4 __attribute__((ext_vector_type(4)));
typedef unsigned int u32x2 __attribute__((ext_vector_type(2)));

#define AS1 __attribute__((address_space(1)))
#define AS3 __attribute__((address_space(3)))

__device__ __forceinline__ void gload_lds16(const void* g, void* l) {
  __builtin_amdgcn_global_load_lds((const AS1 unsigned int*)g, (AS3 unsigned int*)l, 16, 0, 0);
}

__device__ __forceinline__ unsigned lds_u32(const void* p) {
  return (unsigned)(uintptr_t)p;
}

__device__ __forceinline__ float gelu_f(float x) {
  return 0.5f * x * (1.0f + erff(x * 0.70710678118654752440f));
}

// DPP row-rotate (16-lane granularity). CTRL = 0x120 + n for ROW_ROR:n.
// All lanes valid for ror -> old operand irrelevant; full row/bank masks.
template <int CTRL>
__device__ __forceinline__ float dppf(float v) {
  return __builtin_bit_cast(float, __builtin_amdgcn_update_dpp(
      __builtin_bit_cast(int, v), __builtin_bit_cast(int, v), CTRL, 0xF, 0xF, false));
}

// ---------------- f32 -> bf16 cast ----------------
__global__ void cast_kernel(const float* __restrict__ in, bf16_t* __restrict__ out, int n4) {
  const int stride = gridDim.x * blockDim.x;
  for (int i = blockIdx.x * blockDim.x + threadIdx.x; i < n4; i += stride) {
    const float4 v = *(const float4*)(in + (size_t)i * 4);
    bf16x4 o;
    o[0] = (bf16_t)v.x; o[1] = (bf16_t)v.y; o[2] = (bf16_t)v.z; o[3] = (bf16_t)v.w;
    *(bf16x4*)(out + (size_t)i * 4) = o;
  }
}

// ---------------- embedding ----------------
__global__ void embed_kernel(const int* __restrict__ seq, const float* __restrict__ emb,
                             const float* __restrict__ pos, float* __restrict__ x32,
                             bf16_t* __restrict__ xb) {
  const int r = blockIdx.x;
  const int s = r & 1023;
  const int tok = seq[r];
  const int c = threadIdx.x << 2;
  const float4 e = *(const float4*)(emb + (size_t)tok * kE + c);
  const float4 pz = *(const float4*)(pos + (size_t)s * kE + c);
  float4 v;
  v.x = e.x * 32.0f + pz.x;
  v.y = e.y * 32.0f + pz.y;
  v.z = e.z * 32.0f + pz.z;
  v.w = e.w * 32.0f + pz.w;
  *(float4*)(x32 + (size_t)r * kE + c) = v;
  bf16x4 o;
  o[0] = (bf16_t)v.x; o[1] = (bf16_t)v.y; o[2] = (bf16_t)v.z; o[3] = (bf16_t)v.w;
  *(bf16x4*)(xb + (size_t)r * kE + c) = o;
}

// ---------------- residual add + LayerNorm ----------------
// MODE 0: x32 = LN(x32 + res_bf16), write bf16 copy.
// MODE 1: bf16 out only, no residual (final LN).
// MODE 2: x32 = LN(x32 + sum of 4 bf16 partials + bias2), write bf16 copy.
template <int MODE>
__global__ void addln_kernel(float* __restrict__ x32, const void* __restrict__ res,
                             const float* __restrict__ gg, const float* __restrict__ bb,
                             bf16_t* __restrict__ xb, const float* __restrict__ bias2) {
  __shared__ float red[8];
  const int r = blockIdx.x;
  const int c = threadIdx.x << 2;
  float4 v = *(const float4*)(x32 + (size_t)r * kE + c);
  if (MODE == 0) {
    const bf16x4 t = *(const bf16x4*)((const bf16_t*)res + (size_t)r * kE + c);
    v.x += (float)t[0]; v.y += (float)t[1]; v.z += (float)t[2]; v.w += (float)t[3];
  }
  if (MODE == 2) {
    const bf16_t* p = (const bf16_t*)res;
#pragma unroll
    for (int part = 0; part < 4; ++part) {
      const bf16x4 t = *(const bf16x4*)(p + (size_t)part * kRows * kE + (size_t)r * kE + c);
      v.x += (float)t[0]; v.y += (float)t[1]; v.z += (float)t[2]; v.w += (float)t[3];
    }
    const float4 b2 = *(const float4*)(bias2 + c);
    v.x += b2.x; v.y += b2.y; v.z += b2.z; v.w += b2.w;
  }
  float s = v.x + v.y + v.z + v.w;
  float q = v.x * v.x + v.y * v.y + v.z * v.z + v.w * v.w;
#pragma unroll
  for (int off = 32; off >= 1; off >>= 1) {
    s += __shfl_xor(s, off, 64);
    q += __shfl_xor(q, off, 64);
  }
  const int w = threadIdx.x >> 6, lane = threadIdx.x & 63;
  if (lane == 0) { red[w] = s; red[4 + w] = q; }
  __syncthreads();
  s = red[0] + red[1] + red[2] + red[3];
  q = red[4] + red[5] + red[6] + red[7];
  const float mean = s * (1.0f / 1024.0f);
  const float var = q * (1.0f / 1024.0f) - mean * mean;
  const float rstd = rsqrtf(var + 1e-5f);
  const float4 g4 = *(const float4*)(gg + c);
  const float4 b4 = *(const float4*)(bb + c);
  float4 o;
  o.x = (v.x - mean) * rstd * g4.x + b4.x;
  o.y = (v.y - mean) * rstd * g4.y + b4.y;
  o.z = (v.z - mean) * rstd * g4.z + b4.z;
  o.w = (v.w - mean) * rstd * g4.w + b4.w;
  if (MODE != 1) *(float4*)(x32 + (size_t)r * kE + c) = o;
  bf16x4 ob;
  ob[0] = (bf16_t)o.x; ob[1] = (bf16_t)o.y; ob[2] = (bf16_t)o.z; ob[3] = (bf16_t)o.w;
  *(bf16x4*)(xb + (size_t)r * kE + c) = ob;
}

// ---------------- GEMM 128x128 (m97-style) — logits only ----------------
template <int EPI>
__launch_bounds__(256, 3)
__global__ void gemm_bt_kernel(const bf16_t* __restrict__ A, const bf16_t* __restrict__ Bt,
                               const float* __restrict__ bias, void* __restrict__ Cv,
                               int M, int N, int K) {
  __shared__ bf16_t lA[128 * 32];
  __shared__ bf16_t lB[128 * 32];
  const int tid = threadIdx.x;
  const int w = tid >> 6;
  const int lane = tid & 63;
  const int g = lane >> 4;
  const int lr = lane & 15;
  const int bm0 = blockIdx.y << 7;
  const int bn0 = blockIdx.x << 7;
  const int wm = (w >> 1) << 6;
  const int wn = (w & 1) << 6;

  const int sr = lane >> 2;
  const int sc = (lane & 3) << 4;

  const char* srcA0 = (const char*)(A + (size_t)(bm0 + (w << 5) + sr) * K) + sc;
  const char* srcA1 = (const char*)(A + (size_t)(bm0 + (w << 5) + 16 + sr) * K) + sc;
  const char* srcB0 = (const char*)(Bt + (size_t)(bn0 + (w << 5) + sr) * K) + sc;
  const char* srcB1 = (const char*)(Bt + (size_t)(bn0 + (w << 5) + 16 + sr) * K) + sc;
  bf16_t* dA0 = lA + (size_t)(w << 5) * 32;
  bf16_t* dA1 = lA + (size_t)((w << 5) + 16) * 32;
  bf16_t* dB0 = lB + (size_t)(w << 5) * 32;
  bf16_t* dB1 = lB + (size_t)((w << 5) + 16) * 32;

  f32x4 zz = {0.f, 0.f, 0.f, 0.f};
  f32x4 acc[4][4];
#pragma unroll
  for (int i = 0; i < 4; ++i)
#pragma unroll
    for (int j = 0; j < 4; ++j) acc[i][j] = zz;

  const bf16_t* pa[4];
  const bf16_t* pb[4];
#pragma unroll
  for (int i = 0; i < 4; ++i) {
    pa[i] = lA + (size_t)(wm + i * 16 + lr) * 32 + g * 8;
    pb[i] = lB + (size_t)(wn + i * 16 + lr) * 32 + g * 8;
  }

  const int NT = K >> 5;
  for (int t = 0; t < NT; ++t) {
    gload_lds16(srcA0, dA0);
    gload_lds16(srcA1, dA1);
    gload_lds16(srcB0, dB0);
    gload_lds16(srcB1, dB1);
    srcA0 += 64; srcA1 += 64; srcB0 += 64; srcB1 += 64;
    __syncthreads();
    bf16x8 a[4], b[4];
#pragma unroll
    for (int i = 0; i < 4; ++i) a[i] = *(const bf16x8*)pa[i];
#pragma unroll
    for (int i = 0; i < 4; ++i) b[i] = *(const bf16x8*)pb[i];
#pragma unroll
    for (int i = 0; i < 4; ++i)
#pragma unroll
      for (int j = 0; j < 4; ++j)
        acc[i][j] = __builtin_amdgcn_mfma_f32_16x16x32_bf16(a[i], b[j], acc[i][j], 0, 0, 0);
    __syncthreads();
  }

#pragma unroll
  for (int i = 0; i < 4; ++i) {
#pragma unroll
    for (int j = 0; j < 4; ++j) {
      const int col = bn0 + wn + j * 16 + lr;
      const float bv = bias[col];
#pragma unroll
      for (int rg = 0; rg < 4; ++rg) {
        const int row = bm0 + wm + i * 16 + g * 4 + rg;
        float v = acc[i][j][rg] + bv;
        if (EPI == 1) {
          ((float*)Cv)[(size_t)row * N + col] = v;
        } else {
          ((bf16_t*)Cv)[(size_t)row * N + col] = (bf16_t)v;
        }
      }
    }
  }
}

// ---------------- GEMM 256x256, BK=64, 8 waves, 8-phase counted-vmcnt ----------------
// T2 swizzle (XOR (row&7)<<4 on byte col, pre-applied to global source) +
// T3/T4 (4 phases/K-tile, 1 stage-region/phase, vmcnt(6) once per K-tile) + T5 setprio.
// EPI: 0 = bias->bf16, 2 = bias+GELU->bf16, 3 = nobias->bf16 partial (out += z*zstride)
template <int EPI>
__launch_bounds__(512, 2)
__global__ void gemm256_kernel(const bf16_t* __restrict__ A, const bf16_t* __restrict__ Bt,
                               const float* __restrict__ bias, void* __restrict__ Cv,
                               int ldA, int ldB, int ldC, int kc, size_t zstride) {
  __shared__ bf16_t lA[2][256 * 64];
  __shared__ bf16_t lB[2][256 * 64];
  const int tid = threadIdx.x;
  const int w = tid >> 6, lane = tid & 63, g = lane >> 4, lr = lane & 15;

  // T1: XCD-aware bijective swizzle (all grids have nwg % 8 == 0)
  const int nwg = gridDim.x * gridDim.y;
  const int lin = blockIdx.y * gridDim.x + blockIdx.x;
  const int cpx = nwg >> 3;
  const int swz = (lin & 7) * cpx + (lin >> 3);
  const int bx = swz % gridDim.x, by = swz / gridDim.x;
  const int bm0 = by << 8, bn0 = bx << 8;
  const int wr = w >> 2, wc = w & 3;
  const int wm = wr << 7, wn = wc << 6;
  const int k0 = blockIdx.z * kc;

  // per-lane staging source (swizzle pre-applied: col granule ^ row-within-8)
  const int lrow = lane >> 3, lcol8 = lane & 7;
  const int scol = ((lcol8 ^ lrow) << 3);
  const bf16_t* pA = A + (size_t)(bm0 + lrow) * ldA + k0 + scol;
  const bf16_t* pB = Bt + (size_t)(bn0 + lrow) * ldB + k0 + scol;

  // per-wave stage region row-bases (all multiples of 8)
  const int ra1_0 = w * 8,                        ra1_1 = 128 + w * 8;  // A ih0
  const int ra4_0 = 64 + w * 8,                   ra4_1 = 192 + w * 8;  // A ih1
  const int rb2_0 = (w >> 2) * 64 + (w & 3) * 8,  rb2_1 = rb2_0 + 128;  // B jh0
  const int rb3_0 = rb2_0 + 32,                   rb3_1 = rb2_1 + 32;   // B jh1

#define STG_A(bufi, t, rb) gload_lds16(pA + (size_t)(rb) * ldA + (t) * 64, &lA[bufi][(rb) * 64])
#define STG_B(bufi, t, rb) gload_lds16(pB + (size_t)(rb) * ldB + (t) * 64, &lB[bufi][(rb) * 64])
#define STAGE_R1(bufi, t) { STG_A(bufi, t, ra1_0); STG_A(bufi, t, ra1_1); }
#define STAGE_R2(bufi, t) { STG_B(bufi, t, rb2_0); STG_B(bufi, t, rb2_1); }
#define STAGE_R3(bufi, t) { STG_B(bufi, t, rb3_0); STG_B(bufi, t, rb3_1); }
#define STAGE_R4(bufi, t) { STG_A(bufi, t, ra4_0); STG_A(bufi, t, ra4_1); }

  // swizzled ds_read column offsets (elements)
  const int cs0 = (g * 8) ^ ((lr & 7) << 3);
  const int cs1 = (32 + g * 8) ^ ((lr & 7) << 3);
#define LDA8(bufi, row, cs) (*(const bf16x8*)&lA[bufi][(row) * 64 + (cs)])
#define LDB8(bufi, row, cs) (*(const bf16x8*)&lB[bufi][(row) * 64 + (cs)])

#define PH_MID()                                          \
  __builtin_amdgcn_sched_barrier(0);                      \
  __builtin_amdgcn_s_barrier();                           \
  asm volatile("s_waitcnt lgkmcnt(0)" ::: "memory");      \
  __builtin_amdgcn_sched_barrier(0);                      \
  __builtin_amdgcn_s_setprio(1)

#define PH_END()                                          \
  __builtin_amdgcn_s_setprio(0);                          \
  __builtin_amdgcn_sched_barrier(0);                      \
  __builtin_amdgcn_s_barrier();                           \
  __builtin_amdgcn_sched_barrier(0)

#define PH_END_VM()                                       \
  __builtin_amdgcn_s_setprio(0);                          \
  __builtin_amdgcn_sched_barrier(0);                      \
  asm volatile("s_waitcnt vmcnt(6)" ::: "memory");        \
  __builtin_amdgcn_s_barrier();                           \
  __builtin_amdgcn_sched_barrier(0)

  f32x4 zz = {0.f, 0.f, 0.f, 0.f};
  f32x4 acc[8][4];
#pragma unroll
  for (int i = 0; i < 8; ++i)
#pragma unroll
    for (int j = 0; j < 4; ++j) acc[i][j] = zz;

  const int NT = kc >> 6;  // >= 2 required (here 4 or 16)

  // prologue: R1..R4 of tile0, R1..R3 of tile1; then tile0 fully landed.
  STAGE_R1(0, 0); STAGE_R2(0, 0); STAGE_R3(0, 0); STAGE_R4(0, 0);
  STAGE_R1(1, 1); STAGE_R2(1, 1); STAGE_R3(1, 1);
  asm volatile("s_waitcnt vmcnt(6)" ::: "memory");
  __builtin_amdgcn_s_barrier();
  __builtin_amdgcn_sched_barrier(0);

  bf16x8 a0[4][2], a1[4][2], b[4][2];

  for (int t = 0; t < NT; ++t) {
    const int bz = t & 1;
    // ---------------- P1 ----------------
#pragma unroll
    for (int i = 0; i < 4; ++i) {
      a0[i][0] = LDA8(bz, wm + i * 16 + lr, cs0);
      a0[i][1] = LDA8(bz, wm + i * 16 + lr, cs1);
    }
#pragma unroll
    for (int j = 0; j < 2; ++j) {
      b[j][0] = LDB8(bz, wn + j * 16 + lr, cs0);
      b[j][1] = LDB8(bz, wn + j * 16 + lr, cs1);
    }
    if (t + 1 < NT) STAGE_R4(bz ^ 1, t + 1);
    PH_MID();
#pragma unroll
    for (int i = 0; i < 4; ++i)
#pragma unroll
      for (int j = 0; j < 2; ++j) {
        acc[i][j] = __builtin_amdgcn_mfma_f32_16x16x32_bf16(a0[i][0], b[j][0], acc[i][j], 0, 0, 0);
        acc[i][j] = __builtin_amdgcn_mfma_f32_16x16x32_bf16(a0[i][1], b[j][1], acc[i][j], 0, 0, 0);
      }
    PH_END();
    // ---------------- P2 ----------------
#pragma unroll
    for (int j = 2; j < 4; ++j) {
      b[j][0] = LDB8(bz, wn + j * 16 + lr, cs0);
      b[j][1] = LDB8(bz, wn + j * 16 + lr, cs1);
    }
    if (t + 2 < NT) STAGE_R1(bz, t + 2);
    PH_MID();
#pragma unroll
    for (int i = 0; i < 4; ++i)
#pragma unroll
      for (int j = 2; j < 4; ++j) {
        acc[i][j] = __builtin_amdgcn_mfma_f32_16x16x32_bf16(a0[i][0], b[j][0], acc[i][j], 0, 0, 0);
        acc[i][j] = __builtin_amdgcn_mfma_f32_16x16x32_bf16(a0[i][1], b[j][1], acc[i][j], 0, 0, 0);
      }
    PH_END();
    // ---------------- P3 ----------------
#pragma unroll
    for (int i = 0; i < 4; ++i) {
      a1[i][0] = LDA8(bz, wm + 64 + i * 16 + lr, cs0);
      a1[i][1] = LDA8(bz, wm + 64 + i * 16 + lr, cs1);
    }
    if (t + 2 < NT) STAGE_R2(bz, t + 2);
    PH_MID();
#pragma unroll
    for (int i = 0; i < 4; ++i)
#pragma unroll
      for (int j = 0; j < 2; ++j) {
        acc[4 + i][j] = __builtin_amdgcn_mfma_f32_16x16x32_bf16(a1[i][0], b[j][0], acc[4 + i][j], 0, 0, 0);
        acc[4 + i][j] = __builtin_amdgcn_mfma_f32_16x16x32_bf16(a1[i][1], b[j][1], acc[4 + i][j], 0, 0, 0);
      }
    PH_END();
    // ---------------- P4 ----------------
    if (t + 2 < NT) STAGE_R3(bz, t + 2);
    PH_MID();
#pragma unroll
    for (int i = 0; i < 4; ++i)
#pragma unroll
      for (int j = 2; j < 4; ++j) {
        acc[4 + i][j] = __builtin_amdgcn_mfma_f32_16x16x32_bf16(a1[i][0], b[j][0], acc[4 + i][j], 0, 0, 0);
        acc[4 + i][j] = __builtin_amdgcn_mfma_f32_16x16x32_bf16(a1[i][1], b[j][1], acc[4 + i][j], 0, 0, 0);
      }
    PH_END_VM();
  }

  // epilogue: C/D layout col = lane&15, row = (lane>>4)*4 + reg
  bf16_t* outb = (bf16_t*)Cv;
  if (EPI == 3) outb += (size_t)blockIdx.z * zstride;
#pragma unroll
  for (int i = 0; i < 8; ++i) {
#pragma unroll
    for (int j = 0; j < 4; ++j) {
      const int col = bn0 + wn + j * 16 + lr;
      float bv = 0.0f;
      if (EPI != 3) bv = bias[col];
#pragma unroll
      for (int rg = 0; rg < 4; ++rg) {
        const int row = bm0 + wm + i * 16 + g * 4 + rg;
        float v = acc[i][j][rg] + bv;
        if (EPI == 2) v = gelu_f(v);
        outb[(size_t)row * ldC + col] = (bf16_t)v;
      }
    }
  }
#undef STG_A
#undef STG_B
#undef STAGE_R1
#undef STAGE_R2
#undef STAGE_R3
#undef STAGE_R4
#undef LDA8
#undef LDB8
#undef PH_MID
#undef PH_END
#undef PH_END_VM
}

// ---------------- fused causal attention with relative-distance bias ----------------
// v3: KVBLK=64 + DPP softmax reductions.
//  - Both 16-lane shuffle trees (max, sum) -> VALU-only DPP row_ror butterflies
//    (removes all 32 ds_bpermute/iter: the dominant LDS-pipe + latency cost).
//  - KV tile 64: one softmax pass per 64 KV cols; heavy block 16 iters (was 32).
//  - K staged to LDS (xor-swizzled, gemm256 pattern), double-buffered, shared by
//    all 4 waves (frees 64-VGPR register prefetch; 4x less K fetch).
//  - V tile 64 rows = two 32-row halves of the tr-read layout (hi half at +4096).
//  - Strict heavy-first dispatch: qt = 15 - (bid>>6) (3 blocks/CU now -> rounds).
__launch_bounds__(256, 3)
__global__ void attn_kernel(const bf16_t* __restrict__ qkv, const int* __restrict__ seq,
                            const float* __restrict__ dist_emb, bf16_t* __restrict__ ctx) {
  __shared__ float sbias[1024];
  __shared__ unsigned char spad[1024];
  __shared__ bf16_t kbuf[2][64 * 64];
  __shared__ bf16_t vbuf[2][4096];
  __shared__ bf16_t pbuf[4][16][72];
  const int tid = threadIdx.x;
  const int w = tid >> 6, lane = tid & 63, g = lane >> 4, lr = lane & 15;
  const int bid = blockIdx.x;
  const int qt = 15 - (bid >> 6);      // heavy blocks dispatch first
  const int h = bid & 15, b = (bid >> 4) & 3;

  const int q0 = qt * 64 + w * 16;
  const bf16_t* qp = qkv + ((size_t)(b * kS + q0 + lr)) * 3072 + h * 64;

  // V staging source (tr-read layout, 32-row half granularity)
  const int p = (w * 64 + lane) * 16;
  const int s_kv = ((p >> 11) << 4) + ((p >> 5) & 15);
  const int s_dv = (((p >> 9) & 3) << 4) + ((p & 31) >> 1);
  const bf16_t* vsrc0 = qkv + ((size_t)(b * kS + s_kv)) * 3072 + 2048 + h * 64 + s_dv;

  // K staging source (xor-swizzle pre-applied to global column granule)
  const int klrow = (w << 3) + (lane >> 3);                 // row within 32-row half
  const int kscol = ((lane & 7) ^ (lane >> 3)) << 3;        // swizzled col granule
  const bf16_t* ksrc0 = qkv + ((size_t)(b * kS + klrow)) * 3072 + 1024 + h * 64 + kscol;

  // swizzled K ds_read column offsets (elements)
  const int cs0k = (g ^ (lr & 7)) << 3;
  const int cs1k = ((4 + g) ^ (lr & 7)) << 3;

  const int* seqb = seq + b * kS;
  const int nt = qt + 1;  // 64-wide KV tiles; covers causal window exactly

#define STAGEKV(bufi, kt_) {                                                        \
    gload_lds16(ksrc0 + (size_t)((kt_) * 64) * 3072, &kbuf[bufi][(w << 3) * 64]);   \
    gload_lds16(ksrc0 + (size_t)((kt_) * 64 + 32) * 3072,                           \
                &kbuf[bufi][(32 + (w << 3)) * 64]);                                 \
    gload_lds16(vsrc0 + (size_t)((kt_) * 64) * 3072, &vbuf[bufi][w << 9]);          \
    gload_lds16(vsrc0 + (size_t)((kt_) * 64 + 32) * 3072,                           \
                &vbuf[bufi][2048 + (w << 9)]);                                      \
  }

  // prologue: tile-0 K+V DMA first, then Q loads + sbias/spad fill hide under it.
  STAGEKV(0, 0);
  const bf16x8 qf0 = *(const bf16x8*)(qp + g * 8);
  const bf16x8 qf1 = *(const bf16x8*)(qp + 32 + g * 8);
  for (int i = tid; i < 1024; i += 256) {
    sbias[i] = dist_emb[i * kH + h];
    spad[i] = (seqb[i] == kV - 1) ? 1 : 0;
  }

  f32x4 zz = {0.f, 0.f, 0.f, 0.f};
  f32x4 oacc[4];
#pragma unroll
  for (int n = 0; n < 4; ++n) oacc[n] = zz;
  float m_[4], l_[4];
#pragma unroll
  for (int j = 0; j < 4; ++j) { m_[j] = -1e30f; l_[j] = 0.f; }

  __syncthreads();  // tile-0 landed, sbias/spad visible

#define ATT_STEP64(kt_, bz) do {                                                    \
    bf16x8 kf0[4], kf1[4];                                                          \
    _Pragma("unroll")                                                               \
    for (int ns = 0; ns < 4; ++ns) {                                                \
      const int krow = (ns * 16 + lr) * 64;                                         \
      kf0[ns] = *(const bf16x8*)&kbuf[bz][krow + cs0k];                             \
      kf1[ns] = *(const bf16x8*)&kbuf[bz][krow + cs1k];                             \
    }                                                                               \
    f32x4 s_[4];                                                                    \
    _Pragma("unroll")                                                               \
    for (int ns = 0; ns < 4; ++ns) {                                                \
      f32x4 z = zz;                                                                 \
      z = __builtin_amdgcn_mfma_f32_16x16x32_bf16(qf0, kf0[ns], z, 0, 0, 0);        \
      z = __builtin_amdgcn_mfma_f32_16x16x32_bf16(qf1, kf1[ns], z, 0, 0, 0);        \
      s_[ns] = z;                                                                   \
    }                                                                               \
    const int colb = (kt_) * 64 + lr;                                               \
    bool pad[4];                                                                    \
    _Pragma("unroll")                                                               \
    for (int ns = 0; ns < 4; ++ns) pad[ns] = spad[colb + ns * 16] != 0;             \
    float sv[4][4], mj[4];                                                          \
    _Pragma("unroll")                                                               \
    for (int j = 0; j < 4; ++j) {                                                   \
      const int r = q0 + g * 4 + j;                                                 \
      _Pragma("unroll")                                                             \
      for (int ns = 0; ns < 4; ++ns) {                                              \
        const int cc = colb + ns * 16;                                              \
        sv[ns][j] = (cc <= r && !pad[ns]) ? s_[ns][j] * 0.125f + sbias[r - cc]      \
                                          : -1e30f;                                 \
      }                                                                             \
      mj[j] = fmaxf(fmaxf(sv[0][j], sv[1][j]), fmaxf(sv[2][j], sv[3][j]));          \
      mj[j] = fmaxf(mj[j], dppf<0x121>(mj[j]));                                     \
      mj[j] = fmaxf(mj[j], dppf<0x122>(mj[j]));                                     \
      mj[j] = fmaxf(mj[j], dppf<0x124>(mj[j]));                                     \
      mj[j] = fmaxf(mj[j], dppf<0x128>(mj[j]));                                     \
    }                                                                               \
    float corr[4], pv[4][4];                                                        \
    _Pragma("unroll")                                                               \
    for (int j = 0; j < 4; ++j) {                                                   \
      const float mn = fmaxf(m_[j], mj[j]);                                         \
      corr[j] = __expf(m_[j] - mn);                                                 \
      m_[j] = mn;                                                                   \
      _Pragma("unroll")                                                             \
      for (int ns = 0; ns < 4; ++ns) pv[ns][j] = __expf(sv[ns][j] - mn);            \
      float rs = (pv[0][j] + pv[1][j]) + (pv[2][j] + pv[3][j]);                     \
      rs += dppf<0x121>(rs);                                                        \
      rs += dppf<0x122>(rs);                                                        \
      rs += dppf<0x124>(rs);                                                        \
      rs += dppf<0x128>(rs);                                                        \
      l_[j] = l_[j] * corr[j] + rs;                                                 \
    }                                                                               \
    _Pragma("unroll")                                                               \
    for (int n = 0; n < 4; ++n) {                                                   \
      f32x4 t = oacc[n];                                                            \
      t[0] *= corr[0]; t[1] *= corr[1]; t[2] *= corr[2]; t[3] *= corr[3];           \
      oacc[n] = t;                                                                  \
    }                                                                               \
    _Pragma("unroll")                                                               \
    for (int j = 0; j < 4; ++j) {                                                   \
      _Pragma("unroll")                                                             \
      for (int ns = 0; ns < 4; ++ns)                                                \
        pbuf[w][g * 4 + j][ns * 16 + lr] = (bf16_t)pv[ns][j];                       \
    }                                                                               \
    asm volatile("s_waitcnt lgkmcnt(0)" ::: "memory");                              \
    const bf16x4 pa0 = *(const bf16x4*)&pbuf[w][lr][g * 4];                         \
    const bf16x4 pa1 = *(const bf16x4*)&pbuf[w][lr][16 + g * 4];                    \
    const bf16x4 pa2 = *(const bf16x4*)&pbuf[w][lr][32 + g * 4];                    \
    const bf16x4 pa3 = *(const bf16x4*)&pbuf[w][lr][48 + g * 4];                    \
    bf16x8 pfl, pfh;                                                                \
    _Pragma("unroll")                                                               \
    for (int j = 0; j < 4; ++j) {                                                   \
      pfl[j] = pa0[j]; pfl[4 + j] = pa1[j];                                         \
      pfh[j] = pa2[j]; pfh[4 + j] = pa3[j];                                         \
    }                                                                               \
    const unsigned vb0 = lds_u32(&vbuf[bz][0]) + g * 128 + lr * 8;                  \
    u32x2 vt[8], vth[8];                                                            \
    _Pragma("unroll")                                                               \
    for (int n = 0; n < 4; ++n) {                                                   \
      asm volatile("ds_read_b64_tr_b16 %0, %2\n\t"                                  \
                   "ds_read_b64_tr_b16 %1, %2 offset:2048"                          \
                   : "=&v"(vt[n * 2]), "=&v"(vt[n * 2 + 1])                         \
                   : "v"(vb0 + n * 512)                                             \
                   : "memory");                                                     \
      asm volatile("ds_read_b64_tr_b16 %0, %2 offset:4096\n\t"                      \
                   "ds_read_b64_tr_b16 %1, %2 offset:6144"                          \
                   : "=&v"(vth[n * 2]), "=&v"(vth[n * 2 + 1])                       \
                   : "v"(vb0 + n * 512)                                             \
                   : "memory");                                                     \
    }                                                                               \
    asm volatile("s_waitcnt lgkmcnt(0)" ::: "memory");                              \
    __builtin_amdgcn_sched_barrier(0);                                              \
    _Pragma("unroll")                                                               \
    for (int n = 0; n < 4; ++n) {                                                   \
      const bf16x4 v0 = __builtin_bit_cast(bf16x4, vt[n * 2]);                      \
      const bf16x4 v1 = __builtin_bit_cast(bf16x4, vt[n * 2 + 1]);                  \
      bf16x8 vf;                                                                    \
      _Pragma("unroll")                                                             \
      for (int j = 0; j < 4; ++j) { vf[j] = v0[j]; vf[4 + j] = v1[j]; }             \
      oacc[n] = __builtin_amdgcn_mfma_f32_16x16x32_bf16(pfl, vf, oacc[n], 0, 0, 0); \
      const bf16x4 h0 = __builtin_bit_cast(bf16x4, vth[n * 2]);                     \
      const bf16x4 h1 = __builtin_bit_cast(bf16x4, vth[n * 2 + 1]);                 \
      bf16x8 vfh;                                                                   \
      _Pragma("unroll")                                                             \
      for (int j = 0; j < 4; ++j) { vfh[j] = h0[j]; vfh[4 + j] = h1[j]; }           \
      oacc[n] = __builtin_amdgcn_mfma_f32_16x16x32_bf16(pfh, vfh, oacc[n], 0, 0, 0);\
    }                                                                               \
  } while (0)

  for (int kt = 0; kt < nt; kt += 2) {
    if (kt + 1 < nt) STAGEKV(1, kt + 1);
    ATT_STEP64(kt, 0);
    __syncthreads();
    if (kt + 2 < nt) STAGEKV(0, kt + 2);
    if (kt + 1 < nt) ATT_STEP64(kt + 1, 1);
    __syncthreads();
  }
#undef ATT_STEP64
#undef STAGEKV

#pragma unroll
  for (int j = 0; j < 4; ++j) {
    const float inv = 1.0f / l_[j];
    const int r = q0 + g * 4 + j;
    bf16_t* dst = ctx + ((size_t)(b * kS + r)) * kE + h * 64;
#pragma unroll
    for (int n = 0; n < 4; ++n) dst[n * 16 + lr] = (bf16_t)(oacc[n][j] * inv);
  }
}

// ---------------- host ----------------
extern "C" void kernel_launch(void* const* d_in, const int* in_sizes, int n_in,
                              void* d_out, int out_size, void* d_ws, size_t ws_size,
                              hipStream_t stream) {
  (void)in_sizes; (void)n_in; (void)out_size;
  const int* seq = (const int*)d_in[0];
  const float* emb = (const float*)d_in[1];
  const float* pos = (const float*)d_in[2];
  const float* dist = (const float*)d_in[3];
  const float* in_w = (const float*)d_in[4];
  const float* in_b = (const float*)d_in[5];
  const float* out_w = (const float*)d_in[6];
  const float* out_b = (const float*)d_in[7];
  const float* ln1g = (const float*)d_in[8];
  const float* ln1b = (const float*)d_in[9];
  const float* ff1w = (const float*)d_in[10];
  const float* ff1b = (const float*)d_in[11];
  const float* ff2w = (const float*)d_in[12];
  const float* ff2b = (const float*)d_in[13];
  const float* ln2g = (const float*)d_in[14];
  const float* ln2b = (const float*)d_in[15];
  const float* lnfg = (const float*)d_in[16];
  const float* lnfb = (const float*)d_in[17];
  const float* genw = (const float*)d_in[18];
  const float* genb = (const float*)d_in[19];

  char* ws = (char*)d_ws;
  size_t off = 0;
  auto alloc = [&](size_t elems, size_t esz) -> void* {
    void* pp = ws + off;
    off += (elems * esz + 255) & ~(size_t)255;
    return pp;
  };
  bf16_t* w_in = (bf16_t*)alloc((size_t)kL * 3 * kE * kE, 2);
  bf16_t* w_out = (bf16_t*)alloc((size_t)kL * kE * kE, 2);
  bf16_t* w_f1 = (bf16_t*)alloc((size_t)kL * kF * kE, 2);
  bf16_t* w_f2 = (bf16_t*)alloc((size_t)kL * kE * kF, 2);
  bf16_t* w_g = (bf16_t*)alloc((size_t)kV * kE, 2);
  float* x32 = (float*)alloc((size_t)kRows * kE, 4);
  bf16_t* xb = (bf16_t*)alloc((size_t)kRows * kE, 2);
  bf16_t* qkvb = (bf16_t*)alloc((size_t)kRows * 3 * kE, 2);
  bf16_t* ctxb = (bf16_t*)alloc((size_t)kRows * kE, 2);
  bf16_t* tmp4 = (bf16_t*)alloc((size_t)4 * kRows * kE, 2);  // split-K partials
  bf16_t* hb = (bf16_t*)alloc((size_t)kRows * kF, 2);
  if (off > ws_size) return;

  cast_kernel<<<2048, 256, 0, stream>>>(in_w, w_in, kL * 3 * kE * kE / 4);
  cast_kernel<<<2048, 256, 0, stream>>>(out_w, w_out, kL * kE * kE / 4);
  cast_kernel<<<2048, 256, 0, stream>>>(ff1w, w_f1, kL * kF * kE / 4);
  cast_kernel<<<2048, 256, 0, stream>>>(ff2w, w_f2, kL * kE * kF / 4);
  cast_kernel<<<1024, 256, 0, stream>>>(genw, w_g, kV * kE / 4);
  embed_kernel<<<kRows, 256, 0, stream>>>(seq, emb, pos, x32, xb);

  for (int l = 0; l < kL; ++l) {
    // QKV: [4096,1024] x [3072,1024]^T -> bf16 [4096,3072]
    gemm256_kernel<0><<<dim3(3 * kE / 256, kRows / 256), 512, 0, stream>>>(
        xb, w_in + (size_t)l * 3 * kE * kE, in_b + (size_t)l * 3 * kE, qkvb,
        kE, kE, 3 * kE, kE, 0);
    attn_kernel<<<kB * kH * 16, 256, 0, stream>>>(qkvb, seq, dist, ctxb);
    // proj: split-K x4 (kc=256) -> 4 bf16 partials; bias folded into addln
    gemm256_kernel<3><<<dim3(kE / 256, kRows / 256, 4), 512, 0, stream>>>(
        ctxb, w_out + (size_t)l * kE * kE, nullptr, tmp4,
        kE, kE, kE, 256, (size_t)kRows * kE);
    addln_kernel<2><<<kRows, 256, 0, stream>>>(x32, tmp4, ln1g + (size_t)l * kE,
                                               ln1b + (size_t)l * kE, xb, out_b + (size_t)l * kE);
    // FF1: [4096,1024] x [4096,1024]^T + bias + GELU -> bf16 [4096,4096]
    gemm256_kernel<2><<<dim3(kF / 256, kRows / 256), 512, 0, stream>>>(
        xb, w_f1 + (size_t)l * kF * kE, ff1b + (size_t)l * kF, hb,
        kE, kE, kF, kE, 0);
    // FF2: split-K x4 (kc=1024): [4096,4096] x [1024,4096]^T -> 4 bf16 partials
    gemm256_kernel<3><<<dim3(kE / 256, kRows / 256, 4), 512, 0, stream>>>(
        hb, w_f2 + (size_t)l * kE * kF, nullptr, tmp4,
        kF, kF, kE, kE, (size_t)kRows * kE);
    addln_kernel<2><<<kRows, 256, 0, stream>>>(x32, tmp4, ln2g + (size_t)l * kE,
                                               ln2b + (size_t)l * kE, xb, ff2b + (size_t)l * kE);
  }
  addln_kernel<1><<<kRows, 256, 0, stream>>>(x32, nullptr, lnfg, lnfb, xb, nullptr);
  gemm_bt_kernel<1><<<dim3(kV / 128, kRows / 128), 256, 0, stream>>>(
      xb, w_g, genb, (float*)d_out, kRows, kV, kE);
}

// Round 3
// 1413.346 us; speedup vs baseline: 1.2422x; 1.0027x over previous
//
#include <hip/hip_runtime.h>
#include <math.h>
#include <stdint.h>

// ---------------- problem constants ----------------
constexpr int kL = 6;
constexpr int kE = 1024;
constexpr int kH = 16;
constexpr int kF = 4096;
constexpr int kV = 1024;
constexpr int kB = 4;
constexpr int kS = 1024;
constexpr int kRows = kB * kS;   // 4096

typedef __bf16 bf16_t;
typedef __bf16 bf16x8 __attribute__((ext_vector_type(8)));
typedef __bf16 bf16x4 __attribute__((ext_vector_type(4)));
typedef float f32x4 __attribute__((ext_vector_type(4)));
typedef unsigned int u32x2 __attribute__((ext_vector_type(2)));

#define AS1 __attribute__((address_space(1)))
#define AS3 __attribute__((address_space(3)))

__device__ __forceinline__ void gload_lds16(const void* g, void* l) {
  __builtin_amdgcn_global_load_lds((const AS1 unsigned int*)g, (AS3 unsigned int*)l, 16, 0, 0);
}

__device__ __forceinline__ unsigned lds_u32(const void* p) {
  return (unsigned)(uintptr_t)p;
}

__device__ __forceinline__ float gelu_f(float x) {
  return 0.5f * x * (1.0f + erff(x * 0.70710678118654752440f));
}

// DPP row-rotate (16-lane granularity). CTRL = 0x120 + n for ROW_ROR:n.
template <int CTRL>
__device__ __forceinline__ float dppf(float v) {
  return __builtin_bit_cast(float, __builtin_amdgcn_update_dpp(
      __builtin_bit_cast(int, v), __builtin_bit_cast(int, v), CTRL, 0xF, 0xF, false));
}

// ---------------- f32 -> bf16 cast ----------------
__global__ void cast_kernel(const float* __restrict__ in, bf16_t* __restrict__ out, int n4) {
  const int stride = gridDim.x * blockDim.x;
  for (int i = blockIdx.x * blockDim.x + threadIdx.x; i < n4; i += stride) {
    const float4 v = *(const float4*)(in + (size_t)i * 4);
    bf16x4 o;
    o[0] = (bf16_t)v.x; o[1] = (bf16_t)v.y; o[2] = (bf16_t)v.z; o[3] = (bf16_t)v.w;
    *(bf16x4*)(out + (size_t)i * 4) = o;
  }
}

// ---------------- embedding ----------------
__global__ void embed_kernel(const int* __restrict__ seq, const float* __restrict__ emb,
                             const float* __restrict__ pos, float* __restrict__ x32,
                             bf16_t* __restrict__ xb) {
  const int r = blockIdx.x;
  const int s = r & 1023;
  const int tok = seq[r];
  const int c = threadIdx.x << 2;
  const float4 e = *(const float4*)(emb + (size_t)tok * kE + c);
  const float4 pz = *(const float4*)(pos + (size_t)s * kE + c);
  float4 v;
  v.x = e.x * 32.0f + pz.x;
  v.y = e.y * 32.0f + pz.y;
  v.z = e.z * 32.0f + pz.z;
  v.w = e.w * 32.0f + pz.w;
  *(float4*)(x32 + (size_t)r * kE + c) = v;
  bf16x4 o;
  o[0] = (bf16_t)v.x; o[1] = (bf16_t)v.y; o[2] = (bf16_t)v.z; o[3] = (bf16_t)v.w;
  *(bf16x4*)(xb + (size_t)r * kE + c) = o;
}

// ---------------- residual add + LayerNorm ----------------
// MODE 0: x32 = LN(x32 + res_bf16), write bf16 copy.
// MODE 1: bf16 out only, no residual (final LN).
// MODE 2: x32 = LN(x32 + sum of 4 bf16 partials + bias2), write bf16 copy.
template <int MODE>
__global__ void addln_kernel(float* __restrict__ x32, const void* __restrict__ res,
                             const float* __restrict__ gg, const float* __restrict__ bb,
                             bf16_t* __restrict__ xb, const float* __restrict__ bias2) {
  __shared__ float red[8];
  const int r = blockIdx.x;
  const int c = threadIdx.x << 2;
  float4 v = *(const float4*)(x32 + (size_t)r * kE + c);
  if (MODE == 0) {
    const bf16x4 t = *(const bf16x4*)((const bf16_t*)res + (size_t)r * kE + c);
    v.x += (float)t[0]; v.y += (float)t[1]; v.z += (float)t[2]; v.w += (float)t[3];
  }
  if (MODE == 2) {
    const bf16_t* p = (const bf16_t*)res;
#pragma unroll
    for (int part = 0; part < 4; ++part) {
      const bf16x4 t = *(const bf16x4*)(p + (size_t)part * kRows * kE + (size_t)r * kE + c);
      v.x += (float)t[0]; v.y += (float)t[1]; v.z += (float)t[2]; v.w += (float)t[3];
    }
    const float4 b2 = *(const float4*)(bias2 + c);
    v.x += b2.x; v.y += b2.y; v.z += b2.z; v.w += b2.w;
  }
  float s = v.x + v.y + v.z + v.w;
  float q = v.x * v.x + v.y * v.y + v.z * v.z + v.w * v.w;
#pragma unroll
  for (int off = 32; off >= 1; off >>= 1) {
    s += __shfl_xor(s, off, 64);
    q += __shfl_xor(q, off, 64);
  }
  const int w = threadIdx.x >> 6, lane = threadIdx.x & 63;
  if (lane == 0) { red[w] = s; red[4 + w] = q; }
  __syncthreads();
  s = red[0] + red[1] + red[2] + red[3];
  q = red[4] + red[5] + red[6] + red[7];
  const float mean = s * (1.0f / 1024.0f);
  const float var = q * (1.0f / 1024.0f) - mean * mean;
  const float rstd = rsqrtf(var + 1e-5f);
  const float4 g4 = *(const float4*)(gg + c);
  const float4 b4 = *(const float4*)(bb + c);
  float4 o;
  o.x = (v.x - mean) * rstd * g4.x + b4.x;
  o.y = (v.y - mean) * rstd * g4.y + b4.y;
  o.z = (v.z - mean) * rstd * g4.z + b4.z;
  o.w = (v.w - mean) * rstd * g4.w + b4.w;
  if (MODE != 1) *(float4*)(x32 + (size_t)r * kE + c) = o;
  bf16x4 ob;
  ob[0] = (bf16_t)o.x; ob[1] = (bf16_t)o.y; ob[2] = (bf16_t)o.z; ob[3] = (bf16_t)o.w;
  *(bf16x4*)(xb + (size_t)r * kE + c) = ob;
}

// ---------------- GEMM 128x128, BK=32, 4 waves (m97 structure, 3 blocks/CU) ----------
// Generalized: ldA/ldB/ldC element strides, kc = K-slice per z-block (split-K),
// bijective XCD swizzle (all grids have nwg % 8 == 0).
// EPI: 0 = bias->bf16, 1 = bias->f32 (logits), 2 = bias+GELU->bf16,
//      3 = no-bias->bf16 partial at Cv + blockIdx.z*zstride.
template <int EPI>
__launch_bounds__(256, 3)
__global__ void gemm128_kernel(const bf16_t* __restrict__ A, const bf16_t* __restrict__ Bt,
                               const float* __restrict__ bias, void* __restrict__ Cv,
                               int ldA, int ldB, int ldC, int kc, size_t zstride) {
  __shared__ bf16_t lA[128 * 32];
  __shared__ bf16_t lB[128 * 32];
  const int tid = threadIdx.x;
  const int w = tid >> 6;
  const int lane = tid & 63;
  const int g = lane >> 4;
  const int lr = lane & 15;

  // T1: XCD-aware bijective swizzle over (x,y); z-planes shift by multiple of 8.
  const int nwg = gridDim.x * gridDim.y;
  const int lin = blockIdx.y * gridDim.x + blockIdx.x;
  const int cpx = nwg >> 3;
  const int swz = (lin & 7) * cpx + (lin >> 3);
  const int bx = swz % gridDim.x, by = swz / gridDim.x;
  const int bm0 = by << 7;
  const int bn0 = bx << 7;
  const int k0 = blockIdx.z * kc;
  const int wm = (w >> 1) << 6;
  const int wn = (w & 1) << 6;

  const int sr = lane >> 2;
  const int sc = (lane & 3) << 4;   // bytes within the 64B (32-elem) K-row slice

  const char* srcA0 = (const char*)(A + (size_t)(bm0 + (w << 5) + sr) * ldA + k0) + sc;
  const char* srcA1 = (const char*)(A + (size_t)(bm0 + (w << 5) + 16 + sr) * ldA + k0) + sc;
  const char* srcB0 = (const char*)(Bt + (size_t)(bn0 + (w << 5) + sr) * ldB + k0) + sc;
  const char* srcB1 = (const char*)(Bt + (size_t)(bn0 + (w << 5) + 16 + sr) * ldB + k0) + sc;
  bf16_t* dA0 = lA + (size_t)(w << 5) * 32;
  bf16_t* dA1 = lA + (size_t)((w << 5) + 16) * 32;
  bf16_t* dB0 = lB + (size_t)(w << 5) * 32;
  bf16_t* dB1 = lB + (size_t)((w << 5) + 16) * 32;

  f32x4 zz = {0.f, 0.f, 0.f, 0.f};
  f32x4 acc[4][4];
#pragma unroll
  for (int i = 0; i < 4; ++i)
#pragma unroll
    for (int j = 0; j < 4; ++j) acc[i][j] = zz;

  const bf16_t* pa[4];
  const bf16_t* pb[4];
#pragma unroll
  for (int i = 0; i < 4; ++i) {
    pa[i] = lA + (size_t)(wm + i * 16 + lr) * 32 + g * 8;
    pb[i] = lB + (size_t)(wn + i * 16 + lr) * 32 + g * 8;
  }

  const int NT = kc >> 5;
  for (int t = 0; t < NT; ++t) {
    gload_lds16(srcA0, dA0);
    gload_lds16(srcA1, dA1);
    gload_lds16(srcB0, dB0);
    gload_lds16(srcB1, dB1);
    srcA0 += 64; srcA1 += 64; srcB0 += 64; srcB1 += 64;
    __syncthreads();
    bf16x8 a[4], b[4];
#pragma unroll
    for (int i = 0; i < 4; ++i) a[i] = *(const bf16x8*)pa[i];
#pragma unroll
    for (int i = 0; i < 4; ++i) b[i] = *(const bf16x8*)pb[i];
#pragma unroll
    for (int i = 0; i < 4; ++i)
#pragma unroll
      for (int j = 0; j < 4; ++j)
        acc[i][j] = __builtin_amdgcn_mfma_f32_16x16x32_bf16(a[i], b[j], acc[i][j], 0, 0, 0);
    __syncthreads();
  }

  // epilogue: C/D layout col = lane&15, row = (lane>>4)*4 + reg
  bf16_t* outb = (bf16_t*)Cv;
  if (EPI == 3) outb += (size_t)blockIdx.z * zstride;
#pragma unroll
  for (int i = 0; i < 4; ++i) {
#pragma unroll
    for (int j = 0; j < 4; ++j) {
      const int col = bn0 + wn + j * 16 + lr;
      float bv = 0.0f;
      if (EPI != 3) bv = bias[col];
#pragma unroll
      for (int rg = 0; rg < 4; ++rg) {
        const int row = bm0 + wm + i * 16 + g * 4 + rg;
        float v = acc[i][j][rg] + bv;
        if (EPI == 2) v = gelu_f(v);
        if (EPI == 1) {
          ((float*)Cv)[(size_t)row * ldC + col] = v;
        } else {
          outb[(size_t)row * ldC + col] = (bf16_t)v;
        }
      }
    }
  }
}

// ---------------- fused causal attention with relative-distance bias ----------------
// v3: KVBLK=64 + DPP softmax reductions (see round-2 notes). Unchanged this round.
__launch_bounds__(256, 3)
__global__ void attn_kernel(const bf16_t* __restrict__ qkv, const int* __restrict__ seq,
                            const float* __restrict__ dist_emb, bf16_t* __restrict__ ctx) {
  __shared__ float sbias[1024];
  __shared__ unsigned char spad[1024];
  __shared__ bf16_t kbuf[2][64 * 64];
  __shared__ bf16_t vbuf[2][4096];
  __shared__ bf16_t pbuf[4][16][72];
  const int tid = threadIdx.x;
  const int w = tid >> 6, lane = tid & 63, g = lane >> 4, lr = lane & 15;
  const int bid = blockIdx.x;
  const int qt = 15 - (bid >> 6);      // heavy blocks dispatch first
  const int h = bid & 15, b = (bid >> 4) & 3;

  const int q0 = qt * 64 + w * 16;
  const bf16_t* qp = qkv + ((size_t)(b * kS + q0 + lr)) * 3072 + h * 64;

  // V staging source (tr-read layout, 32-row half granularity)
  const int p = (w * 64 + lane) * 16;
  const int s_kv = ((p >> 11) << 4) + ((p >> 5) & 15);
  const int s_dv = (((p >> 9) & 3) << 4) + ((p & 31) >> 1);
  const bf16_t* vsrc0 = qkv + ((size_t)(b * kS + s_kv)) * 3072 + 2048 + h * 64 + s_dv;

  // K staging source (xor-swizzle pre-applied to global column granule)
  const int klrow = (w << 3) + (lane >> 3);
  const int kscol = ((lane & 7) ^ (lane >> 3)) << 3;
  const bf16_t* ksrc0 = qkv + ((size_t)(b * kS + klrow)) * 3072 + 1024 + h * 64 + kscol;

  // swizzled K ds_read column offsets (elements)
  const int cs0k = (g ^ (lr & 7)) << 3;
  const int cs1k = ((4 + g) ^ (lr & 7)) << 3;

  const int* seqb = seq + b * kS;
  const int nt = qt + 1;

#define STAGEKV(bufi, kt_) {                                                        \
    gload_lds16(ksrc0 + (size_t)((kt_) * 64) * 3072, &kbuf[bufi][(w << 3) * 64]);   \
    gload_lds16(ksrc0 + (size_t)((kt_) * 64 + 32) * 3072,                           \
                &kbuf[bufi][(32 + (w << 3)) * 64]);                                 \
    gload_lds16(vsrc0 + (size_t)((kt_) * 64) * 3072, &vbuf[bufi][w << 9]);          \
    gload_lds16(vsrc0 + (size_t)((kt_) * 64 + 32) * 3072,                           \
                &vbuf[bufi][2048 + (w << 9)]);                                      \
  }

  STAGEKV(0, 0);
  const bf16x8 qf0 = *(const bf16x8*)(qp + g * 8);
  const bf16x8 qf1 = *(const bf16x8*)(qp + 32 + g * 8);
  for (int i = tid; i < 1024; i += 256) {
    sbias[i] = dist_emb[i * kH + h];
    spad[i] = (seqb[i] == kV - 1) ? 1 : 0;
  }

  f32x4 zz = {0.f, 0.f, 0.f, 0.f};
  f32x4 oacc[4];
#pragma unroll
  for (int n = 0; n < 4; ++n) oacc[n] = zz;
  float m_[4], l_[4];
#pragma unroll
  for (int j = 0; j < 4; ++j) { m_[j] = -1e30f; l_[j] = 0.f; }

  __syncthreads();

#define ATT_STEP64(kt_, bz) do {                                                    \
    bf16x8 kf0[4], kf1[4];                                                          \
    _Pragma("unroll")                                                               \
    for (int ns = 0; ns < 4; ++ns) {                                                \
      const int krow = (ns * 16 + lr) * 64;                                         \
      kf0[ns] = *(const bf16x8*)&kbuf[bz][krow + cs0k];                             \
      kf1[ns] = *(const bf16x8*)&kbuf[bz][krow + cs1k];                             \
    }                                                                               \
    f32x4 s_[4];                                                                    \
    _Pragma("unroll")                                                               \
    for (int ns = 0; ns < 4; ++ns) {                                                \
      f32x4 z = zz;                                                                 \
      z = __builtin_amdgcn_mfma_f32_16x16x32_bf16(qf0, kf0[ns], z, 0, 0, 0);        \
      z = __builtin_amdgcn_mfma_f32_16x16x32_bf16(qf1, kf1[ns], z, 0, 0, 0);        \
      s_[ns] = z;                                                                   \
    }                                                                               \
    const int colb = (kt_) * 64 + lr;                                               \
    bool pad[4];                                                                    \
    _Pragma("unroll")                                                               \
    for (int ns = 0; ns < 4; ++ns) pad[ns] = spad[colb + ns * 16] != 0;             \
    float sv[4][4], mj[4];                                                          \
    _Pragma("unroll")                                                               \
    for (int j = 0; j < 4; ++j) {                                                   \
      const int r = q0 + g * 4 + j;                                                 \
      _Pragma("unroll")                                                             \
      for (int ns = 0; ns < 4; ++ns) {                                              \
        const int cc = colb + ns * 16;                                              \
        sv[ns][j] = (cc <= r && !pad[ns]) ? s_[ns][j] * 0.125f + sbias[r - cc]      \
                                          : -1e30f;                                 \
      }                                                                             \
      mj[j] = fmaxf(fmaxf(sv[0][j], sv[1][j]), fmaxf(sv[2][j], sv[3][j]));          \
      mj[j] = fmaxf(mj[j], dppf<0x121>(mj[j]));                                     \
      mj[j] = fmaxf(mj[j], dppf<0x122>(mj[j]));                                     \
      mj[j] = fmaxf(mj[j], dppf<0x124>(mj[j]));                                     \
      mj[j] = fmaxf(mj[j], dppf<0x128>(mj[j]));                                     \
    }                                                                               \
    float corr[4], pv[4][4];                                                        \
    _Pragma("unroll")                                                               \
    for (int j = 0; j < 4; ++j) {                                                   \
      const float mn = fmaxf(m_[j], mj[j]);                                         \
      corr[j] = __expf(m_[j] - mn);                                                 \
      m_[j] = mn;                                                                   \
      _Pragma("unroll")                                                             \
      for (int ns = 0; ns < 4; ++ns) pv[ns][j] = __expf(sv[ns][j] - mn);            \
      float rs = (pv[0][j] + pv[1][j]) + (pv[2][j] + pv[3][j]);                     \
      rs += dppf<0x121>(rs);                                                        \
      rs += dppf<0x122>(rs);                                                        \
      rs += dppf<0x124>(rs);                                                        \
      rs += dppf<0x128>(rs);                                                        \
      l_[j] = l_[j] * corr[j] + rs;                                                 \
    }                                                                               \
    _Pragma("unroll")                                                               \
    for (int n = 0; n < 4; ++n) {                                                   \
      f32x4 t = oacc[n];                                                            \
      t[0] *= corr[0]; t[1] *= corr[1]; t[2] *= corr[2]; t[3] *= corr[3];           \
      oacc[n] = t;                                                                  \
    }                                                                               \
    _Pragma("unroll")                                                               \
    for (int j = 0; j < 4; ++j) {                                                   \
      _Pragma("unroll")                                                             \
      for (int ns = 0; ns < 4; ++ns)                                                \
        pbuf[w][g * 4 + j][ns * 16 + lr] = (bf16_t)pv[ns][j];                       \
    }                                                                               \
    asm volatile("s_waitcnt lgkmcnt(0)" ::: "memory");                              \
    const bf16x4 pa0 = *(const bf16x4*)&pbuf[w][lr][g * 4];                         \
    const bf16x4 pa1 = *(const bf16x4*)&pbuf[w][lr][16 + g * 4];                    \
    const bf16x4 pa2 = *(const bf16x4*)&pbuf[w][lr][32 + g * 4];                    \
    const bf16x4 pa3 = *(const bf16x4*)&pbuf[w][lr][48 + g * 4];                    \
    bf16x8 pfl, pfh;                                                                \
    _Pragma("unroll")                                                               \
    for (int j = 0; j < 4; ++j) {                                                   \
      pfl[j] = pa0[j]; pfl[4 + j] = pa1[j];                                         \
      pfh[j] = pa2[j]; pfh[4 + j] = pa3[j];                                         \
    }                                                                               \
    const unsigned vb0 = lds_u32(&vbuf[bz][0]) + g * 128 + lr * 8;                  \
    u32x2 vt[8], vth[8];                                                            \
    _Pragma("unroll")                                                               \
    for (int n = 0; n < 4; ++n) {                                                   \
      asm volatile("ds_read_b64_tr_b16 %0, %2\n\t"                                  \
                   "ds_read_b64_tr_b16 %1, %2 offset:2048"                          \
                   : "=&v"(vt[n * 2]), "=&v"(vt[n * 2 + 1])                         \
                   : "v"(vb0 + n * 512)                                             \
                   : "memory");                                                     \
      asm volatile("ds_read_b64_tr_b16 %0, %2 offset:4096\n\t"                      \
                   "ds_read_b64_tr_b16 %1, %2 offset:6144"                          \
                   : "=&v"(vth[n * 2]), "=&v"(vth[n * 2 + 1])                       \
                   : "v"(vb0 + n * 512)                                             \
                   : "memory");                                                     \
    }                                                                               \
    asm volatile("s_waitcnt lgkmcnt(0)" ::: "memory");                              \
    __builtin_amdgcn_sched_barrier(0);                                              \
    _Pragma("unroll")                                                               \
    for (int n = 0; n < 4; ++n) {                                                   \
      const bf16x4 v0 = __builtin_bit_cast(bf16x4, vt[n * 2]);                      \
      const bf16x4 v1 = __builtin_bit_cast(bf16x4, vt[n * 2 + 1]);                  \
      bf16x8 vf;                                                                    \
      _Pragma("unroll")                                                             \
      for (int j = 0; j < 4; ++j) { vf[j] = v0[j]; vf[4 + j] = v1[j]; }             \
      oacc[n] = __builtin_amdgcn_mfma_f32_16x16x32_bf16(pfl, vf, oacc[n], 0, 0, 0); \
      const bf16x4 h0 = __builtin_bit_cast(bf16x4, vth[n * 2]);                     \
      const bf16x4 h1 = __builtin_bit_cast(bf16x4, vth[n * 2 + 1]);                 \
      bf16x8 vfh;                                                                   \
      _Pragma("unroll")                                                             \
      for (int j = 0; j < 4; ++j) { vfh[j] = h0[j]; vfh[4 + j] = h1[j]; }           \
      oacc[n] = __builtin_amdgcn_mfma_f32_16x16x32_bf16(pfh, vfh, oacc[n], 0, 0, 0);\
    }                                                                               \
  } while (0)

  for (int kt = 0; kt < nt; kt += 2) {
    if (kt + 1 < nt) STAGEKV(1, kt + 1);
    ATT_STEP64(kt, 0);
    __syncthreads();
    if (kt + 2 < nt) STAGEKV(0, kt + 2);
    if (kt + 1 < nt) ATT_STEP64(kt + 1, 1);
    __syncthreads();
  }
#undef ATT_STEP64
#undef STAGEKV

#pragma unroll
  for (int j = 0; j < 4; ++j) {
    const float inv = 1.0f / l_[j];
    const int r = q0 + g * 4 + j;
    bf16_t* dst = ctx + ((size_t)(b * kS + r)) * kE + h * 64;
#pragma unroll
    for (int n = 0; n < 4; ++n) dst[n * 16 + lr] = (bf16_t)(oacc[n][j] * inv);
  }
}

// ---------------- host ----------------
extern "C" void kernel_launch(void* const* d_in, const int* in_sizes, int n_in,
                              void* d_out, int out_size, void* d_ws, size_t ws_size,
                              hipStream_t stream) {
  (void)in_sizes; (void)n_in; (void)out_size;
  const int* seq = (const int*)d_in[0];
  const float* emb = (const float*)d_in[1];
  const float* pos = (const float*)d_in[2];
  const float* dist = (const float*)d_in[3];
  const float* in_w = (const float*)d_in[4];
  const float* in_b = (const float*)d_in[5];
  const float* out_w = (const float*)d_in[6];
  const float* out_b = (const float*)d_in[7];
  const float* ln1g = (const float*)d_in[8];
  const float* ln1b = (const float*)d_in[9];
  const float* ff1w = (const float*)d_in[10];
  const float* ff1b = (const float*)d_in[11];
  const float* ff2w = (const float*)d_in[12];
  const float* ff2b = (const float*)d_in[13];
  const float* ln2g = (const float*)d_in[14];
  const float* ln2b = (const float*)d_in[15];
  const float* lnfg = (const float*)d_in[16];
  const float* lnfb = (const float*)d_in[17];
  const float* genw = (const float*)d_in[18];
  const float* genb = (const float*)d_in[19];

  char* ws = (char*)d_ws;
  size_t off = 0;
  auto alloc = [&](size_t elems, size_t esz) -> void* {
    void* pp = ws + off;
    off += (elems * esz + 255) & ~(size_t)255;
    return pp;
  };
  bf16_t* w_in = (bf16_t*)alloc((size_t)kL * 3 * kE * kE, 2);
  bf16_t* w_out = (bf16_t*)alloc((size_t)kL * kE * kE, 2);
  bf16_t* w_f1 = (bf16_t*)alloc((size_t)kL * kF * kE, 2);
  bf16_t* w_f2 = (bf16_t*)alloc((size_t)kL * kE * kF, 2);
  bf16_t* w_g = (bf16_t*)alloc((size_t)kV * kE, 2);
  float* x32 = (float*)alloc((size_t)kRows * kE, 4);
  bf16_t* xb = (bf16_t*)alloc((size_t)kRows * kE, 2);
  bf16_t* qkvb = (bf16_t*)alloc((size_t)kRows * 3 * kE, 2);
  bf16_t* ctxb = (bf16_t*)alloc((size_t)kRows * kE, 2);
  bf16_t* tmp4 = (bf16_t*)alloc((size_t)4 * kRows * kE, 2);  // split-K partials
  bf16_t* hb = (bf16_t*)alloc((size_t)kRows * kF, 2);
  if (off > ws_size) return;

  cast_kernel<<<2048, 256, 0, stream>>>(in_w, w_in, kL * 3 * kE * kE / 4);
  cast_kernel<<<2048, 256, 0, stream>>>(out_w, w_out, kL * kE * kE / 4);
  cast_kernel<<<2048, 256, 0, stream>>>(ff1w, w_f1, kL * kF * kE / 4);
  cast_kernel<<<2048, 256, 0, stream>>>(ff2w, w_f2, kL * kE * kF / 4);
  cast_kernel<<<1024, 256, 0, stream>>>(genw, w_g, kV * kE / 4);
  embed_kernel<<<kRows, 256, 0, stream>>>(seq, emb, pos, x32, xb);

  for (int l = 0; l < kL; ++l) {
    // QKV: [4096,1024] x [3072,1024]^T -> bf16 [4096,3072]; 768 blocks (3/CU)
    gemm128_kernel<0><<<dim3(3 * kE / 128, kRows / 128), 256, 0, stream>>>(
        xb, w_in + (size_t)l * 3 * kE * kE, in_b + (size_t)l * 3 * kE, qkvb,
        kE, kE, 3 * kE, kE, 0);
    attn_kernel<<<kB * kH * 16, 256, 0, stream>>>(qkvb, seq, dist, ctxb);
    // proj: split-K x4 (kc=256) -> 4 bf16 partials; 1024 blocks
    gemm128_kernel<3><<<dim3(kE / 128, kRows / 128, 4), 256, 0, stream>>>(
        ctxb, w_out + (size_t)l * kE * kE, nullptr, tmp4,
        kE, kE, kE, 256, (size_t)kRows * kE);
    addln_kernel<2><<<kRows, 256, 0, stream>>>(x32, tmp4, ln1g + (size_t)l * kE,
                                               ln1b + (size_t)l * kE, xb, out_b + (size_t)l * kE);
    // FF1: [4096,1024] x [4096,1024]^T + bias + GELU -> bf16 [4096,4096]; 1024 blocks
    gemm128_kernel<2><<<dim3(kF / 128, kRows / 128), 256, 0, stream>>>(
        xb, w_f1 + (size_t)l * kF * kE, ff1b + (size_t)l * kF, hb,
        kE, kE, kF, kE, 0);
    // FF2: split-K x4 (kc=1024): [4096,4096] x [1024,4096]^T -> 4 bf16 partials; 1024 blocks
    gemm128_kernel<3><<<dim3(kE / 128, kRows / 128, 4), 256, 0, stream>>>(
        hb, w_f2 + (size_t)l * kE * kF, nullptr, tmp4,
        kF, kF, kE, kE, (size_t)kRows * kE);
    addln_kernel<2><<<kRows, 256, 0, stream>>>(x32, tmp4, ln2g + (size_t)l * kE,
                                               ln2b + (size_t)l * kE, xb, ff2b + (size_t)l * kE);
  }
  addln_kernel<1><<<kRows, 256, 0, stream>>>(x32, nullptr, lnfg, lnfb, xb, nullptr);
  gemm128_kernel<1><<<dim3(kV / 128, kRows / 128), 256, 0, stream>>>(
      xb, w_g, genb, (float*)d_out, kE, kE, kV, kE, 0);
}